// Round 7
// baseline (236.243 us; speedup 1.0000x reference)
//
#include <hip/hip_runtime.h>

typedef unsigned short u16;
typedef __bf16 bf16x8 __attribute__((ext_vector_type(8)));
typedef float f32x4 __attribute__((ext_vector_type(4)));

#define B_ 4
#define L_ 2048
#define LOG2E 1.44269504088896340736f
#define HSTRIDE ((size_t)L_ * 64)   // one (b,t,h) plane: 2048*64 elements

// ---------- helpers ----------
__device__ __forceinline__ u16 f2bf(float f) {
    unsigned u = __float_as_uint(f);
    u += 0x7fff + ((u >> 16) & 1);   // RNE
    return (u16)(u >> 16);
}

__device__ __forceinline__ f32x4 mfma16(bf16x8 a, bf16x8 b, f32x4 c) {
    return __builtin_amdgcn_mfma_f32_16x16x32_bf16(a, b, c, 0, 0, 0);
}

// async global->LDS, 16B per lane; LDS dest is wave-uniform base + lane*16
__device__ __forceinline__ void async16(const u16* g, u16* l) {
    __builtin_amdgcn_global_load_lds(
        (const __attribute__((address_space(1))) u16*)g,
        (__attribute__((address_space(3))) u16*)l, 16, 0, 0);
}

// ---------- kernel 0a: fp32 -> bf16 convert ----------
__global__ __launch_bounds__(256) void convert_f32_bf16(const float* __restrict__ in,
                                                        u16* __restrict__ out, int n) {
    int i = (blockIdx.x * 256 + threadIdx.x) * 4;
    if (i < n) {
        float4 f = *(const float4*)(in + i);
        ushort4 r;
        r.x = f2bf(f.x); r.y = f2bf(f.y); r.z = f2bf(f.z); r.w = f2bf(f.w);
        *(ushort4*)(out + i) = r;
    }
}

// ---------- kernel 0b: x[b][i][l] fp32 -> xbt[b][l][i] bf16 (64x64 LDS tiles) ----------
__global__ __launch_bounds__(256) void transpose_x(const float* __restrict__ x,
                                                   u16* __restrict__ xbt) {
    __shared__ u16 T[64][66];
    int b  = blockIdx.z;
    int i0 = blockIdx.y * 64;   // DIM tile (512/64 = 8)
    int l0 = blockIdx.x * 64;   // L tile  (2048/64 = 32)
    int t  = threadIdx.x;
    int c  = t & 63, r4 = t >> 6;
    const float* xb = x + ((size_t)b * 512 + i0) * 2048 + l0;
#pragma unroll
    for (int r = r4; r < 64; r += 4) T[r][c] = f2bf(xb[(size_t)r * 2048 + c]);
    __syncthreads();
    u16* ob = xbt + ((size_t)b * 2048 + l0) * 512 + i0;
#pragma unroll
    for (int r = r4; r < 64; r += 4) ob[(size_t)r * 512 + c] = T[c][r];
}

// ---------- kernel 1: QKV GEMM  qkv[b,o,l] = sum_i w[o,i] x[b,i,l] ----------
// m = l (128), n = o (128), K = 512, BK = 64.  A = xbt[b][l][i], B = w[o][i].
// Q stored [b][0][h][l][c], pre-scaled by 0.125*LOG2E (exp2-domain logits).
// K stored in MFMA-A(S^T)-fragment order: [b][1][h][ktile(128)][ks(2)][quad][n15][j]
// V stored in MFMA-B(PV)-fragment order:  [b][2][h][kt(16)][ks2(4)][nf2(4)][lane][j]
//   -> attention reads BOTH as single coalesced dwordx4 per fragment, zero barriers.
__global__ __launch_bounds__(256, 2) void qkv_gemm(const u16* __restrict__ xbt,
                                                   const u16* __restrict__ wq,
                                                   u16* __restrict__ qkv) {
    __shared__ u16 smem[16384];          // As[0:8192], Bs[8192:16384]
    u16* As = smem;
    u16* Bs = smem + 8192;
    int b  = blockIdx.z;
    int m0 = blockIdx.x * 128;           // l
    int n0 = blockIdx.y * 128;           // o (0..1535, 128-aligned -> t uniform per block)
    int tid = threadIdx.x;
    int lane = tid & 63, wid = tid >> 6;
    int quad = lane >> 4, n15 = lane & 15;
    const u16* Abase = xbt + ((size_t)b * L_ + m0) * 512;
    const u16* Bbase = wq + (size_t)n0 * 512;
    int mw = (wid & 1) * 64, nw = (wid >> 1) * 64;
    f32x4 acc[4][4] = {};
    for (int k0 = 0; k0 < 512; k0 += 64) {
        __syncthreads();
#pragma unroll
        for (int c = 0; c < 4; ++c) {
            int off = wid * 2048 + c * 512 + lane * 8;
            int row = off >> 6, col = off & 63;
            async16(Abase + (size_t)row * 512 + k0 + col, As + wid * 2048 + c * 512);
            async16(Bbase + (size_t)row * 512 + k0 + col, Bs + wid * 2048 + c * 512);
        }
        __syncthreads();
#pragma unroll
        for (int ks = 0; ks < 2; ++ks) {
            bf16x8 af[4], bfr[4];
#pragma unroll
            for (int i = 0; i < 4; ++i)
                af[i] = *(const bf16x8*)&As[(mw + i * 16 + n15) * 64 + ks * 32 + quad * 8];
#pragma unroll
            for (int j = 0; j < 4; ++j)
                bfr[j] = *(const bf16x8*)&Bs[(nw + j * 16 + n15) * 64 + ks * 32 + quad * 8];
#pragma unroll
            for (int i = 0; i < 4; ++i)
#pragma unroll
                for (int j = 0; j < 4; ++j)
                    acc[i][j] = mfma16(af[i], bfr[j], acc[i][j]);
        }
    }
    if (n0 < 512) {
        // Q: direct store [l][c], scaled by 0.125*LOG2E
#pragma unroll
        for (int i = 0; i < 4; ++i) {
#pragma unroll
            for (int j = 0; j < 4; ++j) {
                int o = n0 + nw + j * 16 + n15;
                int h = (o >> 6) & 7, cc = o & 63;
                u16* dst = qkv + ((size_t)b * 3 * 8 + h) * HSTRIDE + cc;
#pragma unroll
                for (int r = 0; r < 4; ++r) {
                    int l = m0 + mw + i * 16 + quad * 4 + r;
                    dst[(size_t)l * 64] = f2bf(acc[i][j][r] * (0.125f * LOG2E));
                }
            }
        }
    } else if (n0 < 1024) {
        // K: store in S^T-A-fragment order [tile][ks][quad_k][n15_k][j]
#pragma unroll
        for (int i = 0; i < 4; ++i) {
            int tile = (m0 + mw + i * 16) >> 4;       // block-uniform per i
#pragma unroll
            for (int j = 0; j < 4; ++j) {
                int o = n0 + nw + j * 16 + n15;
                int h = (o >> 6) & 7, c = o & 63;
                int ks_k = c >> 5, qk = (c >> 3) & 3, jj = c & 7;
                u16* dst = qkv + (((size_t)b * 3 + 1) * 8 + h) * HSTRIDE
                         + ((size_t)tile * 2 + ks_k) * 512 + qk * 128 + jj;
#pragma unroll
                for (int r = 0; r < 4; ++r) {
                    int n15k = quad * 4 + r;          // l & 15
                    dst[n15k * 8] = f2bf(acc[i][j][r]);
                }
            }
        }
    } else {
        // V: store directly in PV-B-fragment order (no LDS transpose, no barriers)
        // offset(l,c) = (l>>7)*8192 + ((l>>5)&3)*2048 + (c>>4)*512
        //             + ((l>>3)&3)*128 + (c&15)*8 + (l&7);  c&15 == n15 here.
        int kt = m0 >> 7;
        u16* Vf = qkv + ((size_t)b * 3 + 2) * 8 * HSTRIDE;
#pragma unroll
        for (int i = 0; i < 4; ++i) {
            int L0 = mw + i * 16;                     // m0 is 128-aligned: drops out of &3
            int ks2 = (L0 >> 5) & 3;
            int r3 = ((L0 >> 3) + (quad >> 1)) & 3;
#pragma unroll
            for (int j = 0; j < 4; ++j) {
                int oo = (n0 - 1024) + nw + j * 16 + n15;
                int h = oo >> 6, c = oo & 63;
                ushort4 pk;
                pk.x = f2bf(acc[i][j][0]); pk.y = f2bf(acc[i][j][1]);
                pk.z = f2bf(acc[i][j][2]); pk.w = f2bf(acc[i][j][3]);
                *(ushort4*)&Vf[(size_t)h * HSTRIDE + kt * 8192 + ks2 * 2048
                               + (c >> 4) * 512 + r3 * 128 + n15 * 8 + (quad & 1) * 4] = pk;
            }
        }
    }
}

// ---------- kernel 2: attention, one block = (b,h) x 128 q-rows, 32 rows/wave ----------
// ZERO barriers: K and V are read as pre-arranged MFMA fragments straight from
// global (wave-uniform addresses -> L1-shared across waves); P round-trips through
// a wave-private LDS slice (per-wave DS ordering makes it race-free). Waves
// free-run, so VMEM / LDS / VALU / MFMA pipes overlap across the 8 waves/CU
// instead of being convoyed by __syncthreads into additive phases (R4/R6 lesson).
// No online softmax (logits O(1), exp2 can't overflow): per-lane row-sum partials,
// cross-quad shfl reduction + shfl broadcast in the epilogue only.
__global__ __launch_bounds__(256, 2) void attn_kernel(const u16* __restrict__ qkv,
                                                      u16* __restrict__ o2) {
    __shared__ u16 Ps[128 * 140];   // 35 KB; stride 140 -> conflict-free phases
    int bh = blockIdx.y;
    int b = bh >> 3, h = bh & 7;
    int q0 = blockIdx.x * 128;
    int tid = threadIdx.x, lane = tid & 63, wid = tid >> 6;
    int quad = lane >> 4, n15 = lane & 15;
    const u16* Qp = qkv + (((size_t)b * 3 + 0) * 8 + h) * HSTRIDE;   // [l][c]
    const u16* Kf = qkv + (((size_t)b * 3 + 1) * 8 + h) * HSTRIDE;   // S^T-A frag order
    const u16* Vf = qkv + (((size_t)b * 3 + 2) * 8 + h) * HSTRIDE;   // PV-B frag order
    int mw = wid * 32;
    u16* Pw = Ps + mw * 140;        // this wave's private 32-row slice

    // Q fragments from global (once); B-operand layout [n=qrow][k=c]
    bf16x8 aq[2][2];
#pragma unroll
    for (int mf = 0; mf < 2; ++mf)
#pragma unroll
        for (int ks = 0; ks < 2; ++ks)
            aq[mf][ks] = *(const bf16x8*)
                &Qp[(size_t)(q0 + mw + mf * 16 + n15) * 64 + ks * 32 + quad * 8];

    f32x4 oacc[2][4] = {};
    float lsumT[2] = {0.f, 0.f};

    for (int kt = 0; kt < 16; ++kt) {
        // S^T = K Q^T ; K fragments: one coalesced dwordx4 each, independent loads
#pragma unroll
        for (int nf = 0; nf < 8; ++nf) {
            f32x4 sT[2] = {};
#pragma unroll
            for (int ks = 0; ks < 2; ++ks) {
                bf16x8 ak = *(const bf16x8*)
                    &Kf[(size_t)((kt * 8 + nf) * 2 + ks) * 512 + lane * 8];
                sT[0] = mfma16(ak, aq[0][ks], sT[0]);
                sT[1] = mfma16(ak, aq[1][ks], sT[1]);
            }
            // p = exp2(s); accumulate row-sum partials; P -> wave-private LDS (b64)
#pragma unroll
            for (int mf = 0; mf < 2; ++mf) {
                float p0 = __builtin_amdgcn_exp2f(sT[mf][0]);
                float p1 = __builtin_amdgcn_exp2f(sT[mf][1]);
                float p2 = __builtin_amdgcn_exp2f(sT[mf][2]);
                float p3 = __builtin_amdgcn_exp2f(sT[mf][3]);
                lsumT[mf] += (p0 + p1) + (p2 + p3);
                ushort4 pk;
                pk.x = f2bf(p0); pk.y = f2bf(p1); pk.z = f2bf(p2); pk.w = f2bf(p3);
                *(ushort4*)&Pw[(mf * 16 + n15) * 140 + nf * 16 + quad * 4] = pk;
            }
        }
        // O += P V ; V fragments: one coalesced dwordx4 each, wave-uniform address
#pragma unroll
        for (int ks2 = 0; ks2 < 4; ++ks2) {
            bf16x8 pa0 = *(const bf16x8*)&Pw[n15 * 140 + ks2 * 32 + quad * 8];
            bf16x8 pa1 = *(const bf16x8*)&Pw[(16 + n15) * 140 + ks2 * 32 + quad * 8];
#pragma unroll
            for (int nf2 = 0; nf2 < 4; ++nf2) {
                bf16x8 vb = *(const bf16x8*)
                    &Vf[(size_t)(kt * 4 + ks2) * 2048 + nf2 * 512 + lane * 8];
                oacc[0][nf2] = mfma16(pa0, vb, oacc[0][nf2]);
                oacc[1][nf2] = mfma16(pa1, vb, oacc[1][nf2]);
            }
        }
    }
    // epilogue: cross-quad reduction (lane covers keys quad*4+r) -> every lane holds
    // the full sum for q-row n15; broadcast row quad*4+r via shfl (no LDS, no masks)
    float inv_[2][4];
#pragma unroll
    for (int mf = 0; mf < 2; ++mf) {
        float s = lsumT[mf];
        s += __shfl_xor(s, 16, 64);
        s += __shfl_xor(s, 32, 64);
#pragma unroll
        for (int r = 0; r < 4; ++r)
            inv_[mf][r] = 1.0f / __shfl(s, (lane & 48) | (quad * 4 + r), 64);
    }
#pragma unroll
    for (int mf = 0; mf < 2; ++mf)
#pragma unroll
        for (int r = 0; r < 4; ++r) {
            float inv = inv_[mf][r];
            int l = q0 + mw + mf * 16 + quad * 4 + r;
#pragma unroll
            for (int nf2 = 0; nf2 < 4; ++nf2) {
                int cc = nf2 * 16 + n15;
                o2[((size_t)b * L_ + l) * 512 + h * 64 + cc] = f2bf(oacc[mf][nf2][r] * inv);
            }
        }
}

// ---------- kernel 3: out GEMM  out[b,o,l] = sum_i w_out[o,i] o2[b,l,i] + b_out[o] ----------
__global__ __launch_bounds__(256, 2) void out_gemm(const u16* __restrict__ wo,
                                                   const u16* __restrict__ o2,
                                                   const float* __restrict__ bout,
                                                   float* __restrict__ out) {
    __shared__ u16 As[8192], Bs[8192];
    int b  = blockIdx.z;
    int m0 = blockIdx.y * 128;   // o
    int n0 = blockIdx.x * 128;   // l
    int tid = threadIdx.x, lane = tid & 63, wid = tid >> 6;
    int quad = lane >> 4, n15 = lane & 15;
    const u16* Abase = wo + (size_t)m0 * 512;
    const u16* Bbase = o2 + ((size_t)b * L_ + n0) * 512;
    int mw = (wid & 1) * 64, nw = (wid >> 1) * 64;
    f32x4 acc[4][4] = {};
    for (int k0 = 0; k0 < 512; k0 += 64) {
        __syncthreads();
#pragma unroll
        for (int c = 0; c < 4; ++c) {
            int off = wid * 2048 + c * 512 + lane * 8;
            int row = off >> 6, col = off & 63;
            async16(Abase + (size_t)row * 512 + k0 + col, As + wid * 2048 + c * 512);
            async16(Bbase + (size_t)row * 512 + k0 + col, Bs + wid * 2048 + c * 512);
        }
        __syncthreads();
#pragma unroll
        for (int ks = 0; ks < 2; ++ks) {
            bf16x8 af[4], bfr[4];
#pragma unroll
            for (int i = 0; i < 4; ++i)
                af[i] = *(const bf16x8*)&As[(mw + i * 16 + n15) * 64 + ks * 32 + quad * 8];
#pragma unroll
            for (int j = 0; j < 4; ++j)
                bfr[j] = *(const bf16x8*)&Bs[(nw + j * 16 + n15) * 64 + ks * 32 + quad * 8];
#pragma unroll
            for (int i = 0; i < 4; ++i)
#pragma unroll
                for (int j = 0; j < 4; ++j)
                    acc[i][j] = mfma16(af[i], bfr[j], acc[i][j]);
        }
    }
#pragma unroll
    for (int i = 0; i < 4; ++i) {
#pragma unroll
        for (int r = 0; r < 4; ++r) {
            int o_ = m0 + mw + i * 16 + quad * 4 + r;
            float bias = bout[o_];
            float* dst = out + ((size_t)b * 512 + o_) * L_ + n0;
#pragma unroll
            for (int j = 0; j < 4; ++j) dst[nw + j * 16 + n15] = acc[i][j][r] + bias;
        }
    }
}

// ---------- workspace layout (u16 elements) ----------
#define OFF_XBT  ((size_t)0)                            // 4*2048*512   = 4194304
#define OFF_WQKV (OFF_XBT + (size_t)B_ * L_ * 512)      // 1536*512     =  786432
#define OFF_WOUT (OFF_WQKV + (size_t)1536 * 512)        // 512*512      =  262144
#define OFF_QKV  (OFF_WOUT + (size_t)512 * 512)         // 3*4*8*2048*64= 12582912
#define OFF_O2   (OFF_QKV + (size_t)3 * B_ * 8 * L_ * 64)  // 4*2048*512

extern "C" void kernel_launch(void* const* d_in, const int* in_sizes, int n_in,
                              void* d_out, int out_size, void* d_ws, size_t ws_size,
                              hipStream_t stream) {
    (void)in_sizes; (void)n_in; (void)out_size; (void)ws_size;
    const float* x    = (const float*)d_in[0];
    const float* wqkv = (const float*)d_in[1];
    const float* wout = (const float*)d_in[2];
    const float* bout = (const float*)d_in[3];
    float* out = (float*)d_out;
    u16* ws = (u16*)d_ws;
    u16* xbt   = ws + OFF_XBT;
    u16* wqkvb = ws + OFF_WQKV;
    u16* woutb = ws + OFF_WOUT;
    u16* qkv   = ws + OFF_QKV;
    u16* o2    = ws + OFF_O2;

    convert_f32_bf16<<<768, 256, 0, stream>>>(wqkv, wqkvb, 1536 * 512);
    convert_f32_bf16<<<256, 256, 0, stream>>>(wout, woutb, 512 * 512);
    transpose_x<<<dim3(32, 8, 4), 256, 0, stream>>>(x, xbt);
    qkv_gemm<<<dim3(16, 12, 4), 256, 0, stream>>>(xbt, wqkvb, qkv);
    attn_kernel<<<dim3(16, 32), 256, 0, stream>>>(qkv, o2);
    out_gemm<<<dim3(16, 4, 4), 256, 0, stream>>>(woutb, o2, bout, out);
}

// Round 8
// 190.907 us; speedup vs baseline: 1.2375x; 1.2375x over previous
//
#include <hip/hip_runtime.h>

typedef unsigned short u16;
typedef __bf16 bf16x8 __attribute__((ext_vector_type(8)));
typedef float f32x4 __attribute__((ext_vector_type(4)));

#define B_ 4
#define L_ 2048
#define LOG2E 1.44269504088896340736f
#define HSTRIDE ((size_t)L_ * 64)   // one (b,t,h) plane: 2048*64 elements

// ---------- helpers ----------
__device__ __forceinline__ u16 f2bf(float f) {
    unsigned u = __float_as_uint(f);
    u += 0x7fff + ((u >> 16) & 1);   // RNE
    return (u16)(u >> 16);
}

__device__ __forceinline__ f32x4 mfma16(bf16x8 a, bf16x8 b, f32x4 c) {
    return __builtin_amdgcn_mfma_f32_16x16x32_bf16(a, b, c, 0, 0, 0);
}

// async global->LDS, 16B per lane; LDS dest is wave-uniform base + lane*16
__device__ __forceinline__ void async16(const u16* g, u16* l) {
    __builtin_amdgcn_global_load_lds(
        (const __attribute__((address_space(1))) u16*)g,
        (__attribute__((address_space(3))) u16*)l, 16, 0, 0);
}

// ---------- kernel 0a: fp32 -> bf16 convert ----------
__global__ __launch_bounds__(256) void convert_f32_bf16(const float* __restrict__ in,
                                                        u16* __restrict__ out, int n) {
    int i = (blockIdx.x * 256 + threadIdx.x) * 4;
    if (i < n) {
        float4 f = *(const float4*)(in + i);
        ushort4 r;
        r.x = f2bf(f.x); r.y = f2bf(f.y); r.z = f2bf(f.z); r.w = f2bf(f.w);
        *(ushort4*)(out + i) = r;
    }
}

// ---------- kernel 0b: x[b][i][l] fp32 -> xbt[b][l][i] bf16 (64x64 LDS tiles) ----------
__global__ __launch_bounds__(256) void transpose_x(const float* __restrict__ x,
                                                   u16* __restrict__ xbt) {
    __shared__ u16 T[64][66];
    int b  = blockIdx.z;
    int i0 = blockIdx.y * 64;   // DIM tile (512/64 = 8)
    int l0 = blockIdx.x * 64;   // L tile  (2048/64 = 32)
    int t  = threadIdx.x;
    int c  = t & 63, r4 = t >> 6;
    const float* xb = x + ((size_t)b * 512 + i0) * 2048 + l0;
#pragma unroll
    for (int r = r4; r < 64; r += 4) T[r][c] = f2bf(xb[(size_t)r * 2048 + c]);
    __syncthreads();
    u16* ob = xbt + ((size_t)b * 2048 + l0) * 512 + i0;
#pragma unroll
    for (int r = r4; r < 64; r += 4) ob[(size_t)r * 512 + c] = T[c][r];
}

// ---------- kernel 1: QKV GEMM  qkv[b,o,l] = sum_i w[o,i] x[b,i,l] ----------
// m = l (128), n = o (128), K = 512, BK = 64.  A = xbt[b][l][i], B = w[o][i].
// Q stored [b][0][h][l][c], pre-scaled by 0.125*LOG2E (exp2-domain logits).
// K stored in MFMA-A(S^T)-fragment order: [b][1][h][ktile(128)][ks(2)][quad][n15][j]
// V stored in MFMA-B(PV)-fragment order:  [b][2][h][chunk(64)][nf2(4)][lane][j]
//   -> attention reads BOTH as single coalesced dwordx4 per fragment.
__global__ __launch_bounds__(256, 2) void qkv_gemm(const u16* __restrict__ xbt,
                                                   const u16* __restrict__ wq,
                                                   u16* __restrict__ qkv) {
    __shared__ u16 smem[16384];          // As[0:8192], Bs[8192:16384]
    u16* As = smem;
    u16* Bs = smem + 8192;
    int b  = blockIdx.z;
    int m0 = blockIdx.x * 128;           // l
    int n0 = blockIdx.y * 128;           // o (0..1535, 128-aligned -> t uniform per block)
    int tid = threadIdx.x;
    int lane = tid & 63, wid = tid >> 6;
    int quad = lane >> 4, n15 = lane & 15;
    const u16* Abase = xbt + ((size_t)b * L_ + m0) * 512;
    const u16* Bbase = wq + (size_t)n0 * 512;
    int mw = (wid & 1) * 64, nw = (wid >> 1) * 64;
    f32x4 acc[4][4] = {};
    for (int k0 = 0; k0 < 512; k0 += 64) {
        __syncthreads();
#pragma unroll
        for (int c = 0; c < 4; ++c) {
            int off = wid * 2048 + c * 512 + lane * 8;
            int row = off >> 6, col = off & 63;
            async16(Abase + (size_t)row * 512 + k0 + col, As + wid * 2048 + c * 512);
            async16(Bbase + (size_t)row * 512 + k0 + col, Bs + wid * 2048 + c * 512);
        }
        __syncthreads();
#pragma unroll
        for (int ks = 0; ks < 2; ++ks) {
            bf16x8 af[4], bfr[4];
#pragma unroll
            for (int i = 0; i < 4; ++i)
                af[i] = *(const bf16x8*)&As[(mw + i * 16 + n15) * 64 + ks * 32 + quad * 8];
#pragma unroll
            for (int j = 0; j < 4; ++j)
                bfr[j] = *(const bf16x8*)&Bs[(nw + j * 16 + n15) * 64 + ks * 32 + quad * 8];
#pragma unroll
            for (int i = 0; i < 4; ++i)
#pragma unroll
                for (int j = 0; j < 4; ++j)
                    acc[i][j] = mfma16(af[i], bfr[j], acc[i][j]);
        }
    }
    if (n0 < 512) {
        // Q: direct store [l][c], scaled by 0.125*LOG2E
#pragma unroll
        for (int i = 0; i < 4; ++i) {
#pragma unroll
            for (int j = 0; j < 4; ++j) {
                int o = n0 + nw + j * 16 + n15;
                int h = (o >> 6) & 7, cc = o & 63;
                u16* dst = qkv + ((size_t)b * 3 * 8 + h) * HSTRIDE + cc;
#pragma unroll
                for (int r = 0; r < 4; ++r) {
                    int l = m0 + mw + i * 16 + quad * 4 + r;
                    dst[(size_t)l * 64] = f2bf(acc[i][j][r] * (0.125f * LOG2E));
                }
            }
        }
    } else if (n0 < 1024) {
        // K: store in S^T-A-fragment order [tile][ks][quad_k][n15_k][j]
#pragma unroll
        for (int i = 0; i < 4; ++i) {
            int tile = (m0 + mw + i * 16) >> 4;       // block-uniform per i
#pragma unroll
            for (int j = 0; j < 4; ++j) {
                int o = n0 + nw + j * 16 + n15;
                int h = (o >> 6) & 7, c = o & 63;
                int ks_k = c >> 5, qk = (c >> 3) & 3, jj = c & 7;
                u16* dst = qkv + (((size_t)b * 3 + 1) * 8 + h) * HSTRIDE
                         + ((size_t)tile * 2 + ks_k) * 512 + qk * 128 + jj;
#pragma unroll
                for (int r = 0; r < 4; ++r) {
                    int n15k = quad * 4 + r;          // l & 15
                    dst[n15k * 8] = f2bf(acc[i][j][r]);
                }
            }
        }
    } else {
        // V: store directly in PV-B-fragment order (no LDS transpose, no barriers)
        // chunk = l>>5 (32 keys); within: [nf2 = c>>4][lane = (l&15... see attn)
        // offset(l,c) = (l>>5)*2048 + (c>>4)*512 + ((l>>3)&3)*128 + (c&15)*8 + (l&7)
        int kt = m0 >> 7;
        u16* Vf = qkv + ((size_t)b * 3 + 2) * 8 * HSTRIDE;
#pragma unroll
        for (int i = 0; i < 4; ++i) {
            int L0 = mw + i * 16;
            int ks2 = (L0 >> 5) & 3;
            int r3 = ((L0 >> 3) + (quad >> 1)) & 3;
#pragma unroll
            for (int j = 0; j < 4; ++j) {
                int oo = (n0 - 1024) + nw + j * 16 + n15;
                int h = oo >> 6, c = oo & 63;
                ushort4 pk;
                pk.x = f2bf(acc[i][j][0]); pk.y = f2bf(acc[i][j][1]);
                pk.z = f2bf(acc[i][j][2]); pk.w = f2bf(acc[i][j][3]);
                *(ushort4*)&Vf[(size_t)h * HSTRIDE + kt * 8192 + ks2 * 2048
                               + (c >> 4) * 512 + r3 * 128 + n15 * 8 + (quad & 1) * 4] = pk;
            }
        }
    }
}

// ---------- kernel 2: attention, one block = (b,h) x 64 q-rows; WAVES SPLIT KEYS ----------
// Each wave owns a disjoint 512-key strip for ALL 64 q-rows. Softmax uses fixed
// max=0 (logits O(1) in exp2 domain), so per-wave partial O and row-sums are
// exactly additive -> merge once at the end via LDS. Main loop: ZERO barriers,
// zero K/V read duplication across waves (the R7 failure mode: 8x VMEM).
// P is wave-private LDS, stride 68 u16: b64 writes land 4-per-bank uniform and
// b128 reads 8-per-bank uniform = zero extra LDS cycles.
__global__ __launch_bounds__(256, 2) void attn_kernel(const u16* __restrict__ qkv,
                                                      u16* __restrict__ o2) {
    __shared__ u16 Ps[4 * 64 * 68];      // 34.8 KB; reused as f32 reduction buffer
    __shared__ float Ls[4][64];          // per-wave row-sum partials
    int bh = blockIdx.y;
    int b = bh >> 3, h = bh & 7;
    int q0 = blockIdx.x * 64;
    int tid = threadIdx.x, lane = tid & 63, wid = tid >> 6;
    int quad = lane >> 4, n15 = lane & 15;
    const u16* Qp = qkv + (((size_t)b * 3 + 0) * 8 + h) * HSTRIDE;   // [l][c]
    const u16* Kf = qkv + (((size_t)b * 3 + 1) * 8 + h) * HSTRIDE;   // S^T-A frag order
    const u16* Vf = qkv + (((size_t)b * 3 + 2) * 8 + h) * HSTRIDE;   // PV-B frag order
    u16* Pw = Ps + wid * (64 * 68);      // wave-private P slice: 64 q x 64 keys

    // Q fragments (B-operand for S^T) for all 64 q-rows, loaded once
    bf16x8 aq[4][2];
#pragma unroll
    for (int mf = 0; mf < 4; ++mf)
#pragma unroll
        for (int ks = 0; ks < 2; ++ks)
            aq[mf][ks] = *(const bf16x8*)
                &Qp[(size_t)(q0 + mf * 16 + n15) * 64 + ks * 32 + quad * 8];

    f32x4 oacc[4][4] = {};               // partial O over this wave's keys
    float lsumT[4] = {0.f, 0.f, 0.f, 0.f};

    // wave's key strip: [wid*512, wid*512+512), processed in 64-key chunks
    for (int it = 0; it < 8; ++it) {
        int tile0 = wid * 32 + it * 4;   // 16-key tile index
#pragma unroll
        for (int nf = 0; nf < 4; ++nf) {
            const u16* kb = Kf + (size_t)(tile0 + nf) * 1024;
            bf16x8 ak0 = *(const bf16x8*)&kb[lane * 8];
            bf16x8 ak1 = *(const bf16x8*)&kb[512 + lane * 8];
#pragma unroll
            for (int mf = 0; mf < 4; ++mf) {
                f32x4 sT = {};
                sT = mfma16(ak0, aq[mf][0], sT);
                sT = mfma16(ak1, aq[mf][1], sT);
                float p0 = __builtin_amdgcn_exp2f(sT[0]);
                float p1 = __builtin_amdgcn_exp2f(sT[1]);
                float p2 = __builtin_amdgcn_exp2f(sT[2]);
                float p3 = __builtin_amdgcn_exp2f(sT[3]);
                lsumT[mf] += (p0 + p1) + (p2 + p3);
                ushort4 pk;
                pk.x = f2bf(p0); pk.y = f2bf(p1); pk.z = f2bf(p2); pk.w = f2bf(p3);
                *(ushort4*)&Pw[(mf * 16 + n15) * 68 + nf * 16 + quad * 4] = pk;
            }
        }
        // O += P V for these 64 keys (two 32-key MFMA k-chunks)
#pragma unroll
        for (int sub = 0; sub < 2; ++sub) {
            bf16x8 pa[4];
#pragma unroll
            for (int mf = 0; mf < 4; ++mf)
                pa[mf] = *(const bf16x8*)&Pw[(mf * 16 + n15) * 68 + sub * 32 + quad * 8];
            const u16* vbb = Vf + (size_t)(wid * 16 + it * 2 + sub) * 2048;
#pragma unroll
            for (int nf2 = 0; nf2 < 4; ++nf2) {
                bf16x8 vb = *(const bf16x8*)&vbb[nf2 * 512 + lane * 8];
#pragma unroll
                for (int mf = 0; mf < 4; ++mf)
                    oacc[mf][nf2] = mfma16(pa[mf], vb, oacc[mf][nf2]);
            }
        }
    }

    // ---- cross-wave merge ----
    // row sums: reduce across quads (keys quad*4+r covered by shfl), publish per wave
#pragma unroll
    for (int mf = 0; mf < 4; ++mf) {
        float s = lsumT[mf];
        s += __shfl_xor(s, 16, 64);
        s += __shfl_xor(s, 32, 64);
        Ls[wid][mf * 16 + n15] = s;      // 4 quads write identical value: benign
    }
    float* Ored = (float*)Ps;            // [4 waves][16 rows x stride 68 f32]
#pragma unroll
    for (int mf = 0; mf < 4; ++mf) {
        __syncthreads();                 // mf=0: all waves done with P; else: prev round read
        float* Od = Ored + wid * (16 * 68);
#pragma unroll
        for (int nf2 = 0; nf2 < 4; ++nf2)
#pragma unroll
            for (int r = 0; r < 4; ++r)
                Od[(quad * 4 + r) * 68 + nf2 * 16 + n15] = oacc[mf][nf2][r];
        __syncthreads();
        int row = tid >> 4, c0 = (tid & 15) * 4;
        float4 a0 = *(float4*)&Ored[0 * 1088 + row * 68 + c0];
        float4 a1 = *(float4*)&Ored[1 * 1088 + row * 68 + c0];
        float4 a2 = *(float4*)&Ored[2 * 1088 + row * 68 + c0];
        float4 a3 = *(float4*)&Ored[3 * 1088 + row * 68 + c0];
        float inv = 1.0f / (Ls[0][mf * 16 + row] + Ls[1][mf * 16 + row]
                          + Ls[2][mf * 16 + row] + Ls[3][mf * 16 + row]);
        ushort4 ov;
        ov.x = f2bf((a0.x + a1.x + a2.x + a3.x) * inv);
        ov.y = f2bf((a0.y + a1.y + a2.y + a3.y) * inv);
        ov.z = f2bf((a0.z + a1.z + a2.z + a3.z) * inv);
        ov.w = f2bf((a0.w + a1.w + a2.w + a3.w) * inv);
        *(ushort4*)&o2[((size_t)b * L_ + q0 + mf * 16 + row) * 512 + h * 64 + c0] = ov;
    }
}

// ---------- kernel 3: out GEMM  out[b,o,l] = sum_i w_out[o,i] o2[b,l,i] + b_out[o] ----------
__global__ __launch_bounds__(256, 2) void out_gemm(const u16* __restrict__ wo,
                                                   const u16* __restrict__ o2,
                                                   const float* __restrict__ bout,
                                                   float* __restrict__ out) {
    __shared__ u16 As[8192], Bs[8192];
    int b  = blockIdx.z;
    int m0 = blockIdx.y * 128;   // o
    int n0 = blockIdx.x * 128;   // l
    int tid = threadIdx.x, lane = tid & 63, wid = tid >> 6;
    int quad = lane >> 4, n15 = lane & 15;
    const u16* Abase = wo + (size_t)m0 * 512;
    const u16* Bbase = o2 + ((size_t)b * L_ + n0) * 512;
    int mw = (wid & 1) * 64, nw = (wid >> 1) * 64;
    f32x4 acc[4][4] = {};
    for (int k0 = 0; k0 < 512; k0 += 64) {
        __syncthreads();
#pragma unroll
        for (int c = 0; c < 4; ++c) {
            int off = wid * 2048 + c * 512 + lane * 8;
            int row = off >> 6, col = off & 63;
            async16(Abase + (size_t)row * 512 + k0 + col, As + wid * 2048 + c * 512);
            async16(Bbase + (size_t)row * 512 + k0 + col, Bs + wid * 2048 + c * 512);
        }
        __syncthreads();
#pragma unroll
        for (int ks = 0; ks < 2; ++ks) {
            bf16x8 af[4], bfr[4];
#pragma unroll
            for (int i = 0; i < 4; ++i)
                af[i] = *(const bf16x8*)&As[(mw + i * 16 + n15) * 64 + ks * 32 + quad * 8];
#pragma unroll
            for (int j = 0; j < 4; ++j)
                bfr[j] = *(const bf16x8*)&Bs[(nw + j * 16 + n15) * 64 + ks * 32 + quad * 8];
#pragma unroll
            for (int i = 0; i < 4; ++i)
#pragma unroll
                for (int j = 0; j < 4; ++j)
                    acc[i][j] = mfma16(af[i], bfr[j], acc[i][j]);
        }
    }
#pragma unroll
    for (int i = 0; i < 4; ++i) {
#pragma unroll
        for (int r = 0; r < 4; ++r) {
            int o_ = m0 + mw + i * 16 + quad * 4 + r;
            float bias = bout[o_];
            float* dst = out + ((size_t)b * 512 + o_) * L_ + n0;
#pragma unroll
            for (int j = 0; j < 4; ++j) dst[nw + j * 16 + n15] = acc[i][j][r] + bias;
        }
    }
}

// ---------- workspace layout (u16 elements) ----------
#define OFF_XBT  ((size_t)0)                            // 4*2048*512   = 4194304
#define OFF_WQKV (OFF_XBT + (size_t)B_ * L_ * 512)      // 1536*512     =  786432
#define OFF_WOUT (OFF_WQKV + (size_t)1536 * 512)        // 512*512      =  262144
#define OFF_QKV  (OFF_WOUT + (size_t)512 * 512)         // 3*4*8*2048*64= 12582912
#define OFF_O2   (OFF_QKV + (size_t)3 * B_ * 8 * L_ * 64)  // 4*2048*512

extern "C" void kernel_launch(void* const* d_in, const int* in_sizes, int n_in,
                              void* d_out, int out_size, void* d_ws, size_t ws_size,
                              hipStream_t stream) {
    (void)in_sizes; (void)n_in; (void)out_size; (void)ws_size;
    const float* x    = (const float*)d_in[0];
    const float* wqkv = (const float*)d_in[1];
    const float* wout = (const float*)d_in[2];
    const float* bout = (const float*)d_in[3];
    float* out = (float*)d_out;
    u16* ws = (u16*)d_ws;
    u16* xbt   = ws + OFF_XBT;
    u16* wqkvb = ws + OFF_WQKV;
    u16* woutb = ws + OFF_WOUT;
    u16* qkv   = ws + OFF_QKV;
    u16* o2    = ws + OFF_O2;

    convert_f32_bf16<<<768, 256, 0, stream>>>(wqkv, wqkvb, 1536 * 512);
    convert_f32_bf16<<<256, 256, 0, stream>>>(wout, woutb, 512 * 512);
    transpose_x<<<dim3(32, 8, 4), 256, 0, stream>>>(x, xbt);
    qkv_gemm<<<dim3(16, 12, 4), 256, 0, stream>>>(xbt, wqkvb, qkv);
    attn_kernel<<<dim3(32, 32), 256, 0, stream>>>(qkv, o2);
    out_gemm<<<dim3(16, 4, 4), 256, 0, stream>>>(woutb, o2, bout, out);
}

// Round 9
// 181.543 us; speedup vs baseline: 1.3013x; 1.0516x over previous
//
#include <hip/hip_runtime.h>

typedef unsigned short u16;
typedef __bf16 bf16x8 __attribute__((ext_vector_type(8)));
typedef float f32x4 __attribute__((ext_vector_type(4)));

#define B_ 4
#define L_ 2048
#define LOG2E 1.44269504088896340736f
#define HSTRIDE ((size_t)L_ * 64)   // one (b,t,h) plane: 2048*64 elements

// ---------- helpers ----------
__device__ __forceinline__ u16 f2bf(float f) {
    unsigned u = __float_as_uint(f);
    u += 0x7fff + ((u >> 16) & 1);   // RNE
    return (u16)(u >> 16);
}

// pack two f32 -> two bf16 (truncation) in ONE v_perm_b32
__device__ __forceinline__ unsigned pk2(float a, float b) {
    return __builtin_amdgcn_perm(__float_as_uint(b), __float_as_uint(a), 0x07060302u);
}

__device__ __forceinline__ f32x4 mfma16(bf16x8 a, bf16x8 b, f32x4 c) {
    return __builtin_amdgcn_mfma_f32_16x16x32_bf16(a, b, c, 0, 0, 0);
}

// async global->LDS, 16B per lane; LDS dest is wave-uniform base + lane*16
__device__ __forceinline__ void async16(const u16* g, u16* l) {
    __builtin_amdgcn_global_load_lds(
        (const __attribute__((address_space(1))) u16*)g,
        (__attribute__((address_space(3))) u16*)l, 16, 0, 0);
}

// ---------- kernel 0a: fp32 -> bf16 convert ----------
__global__ __launch_bounds__(256) void convert_f32_bf16(const float* __restrict__ in,
                                                        u16* __restrict__ out, int n) {
    int i = (blockIdx.x * 256 + threadIdx.x) * 4;
    if (i < n) {
        float4 f = *(const float4*)(in + i);
        ushort4 r;
        r.x = f2bf(f.x); r.y = f2bf(f.y); r.z = f2bf(f.z); r.w = f2bf(f.w);
        *(ushort4*)(out + i) = r;
    }
}

// ---------- kernel 0b: x[b][i][l] fp32 -> xbt[b][l][i] bf16 (64x64 LDS tiles) ----------
__global__ __launch_bounds__(256) void transpose_x(const float* __restrict__ x,
                                                   u16* __restrict__ xbt) {
    __shared__ u16 T[64][66];
    int b  = blockIdx.z;
    int i0 = blockIdx.y * 64;   // DIM tile (512/64 = 8)
    int l0 = blockIdx.x * 64;   // L tile  (2048/64 = 32)
    int t  = threadIdx.x;
    int c  = t & 63, r4 = t >> 6;
    const float* xb = x + ((size_t)b * 512 + i0) * 2048 + l0;
#pragma unroll
    for (int r = r4; r < 64; r += 4) T[r][c] = f2bf(xb[(size_t)r * 2048 + c]);
    __syncthreads();
    u16* ob = xbt + ((size_t)b * 2048 + l0) * 512 + i0;
#pragma unroll
    for (int r = r4; r < 64; r += 4) ob[(size_t)r * 512 + c] = T[c][r];
}

// ---------- kernel 1: QKV GEMM  qkv[b,o,l] = sum_i w[o,i] x[b,i,l] ----------
// m = l (128), n = o (128), K = 512, BK = 64.  A = xbt[b][l][i], B = w[o][i].
// Q stored [b][0][h][l][c], pre-scaled by 0.125*LOG2E (exp2-domain logits).
// K stored in MFMA-A(S^T)-fragment order: [b][1][h][ktile(128)][ks(2)][quad][n15][j]
// V stored in MFMA-B(PV)-fragment order:  [b][2][h][chunk(64)][nf2(4)][lane][j]
//   -> attention reads BOTH as single coalesced dwordx4 per fragment.
__global__ __launch_bounds__(256, 2) void qkv_gemm(const u16* __restrict__ xbt,
                                                   const u16* __restrict__ wq,
                                                   u16* __restrict__ qkv) {
    __shared__ u16 smem[16384];          // As[0:8192], Bs[8192:16384]
    u16* As = smem;
    u16* Bs = smem + 8192;
    int b  = blockIdx.z;
    int m0 = blockIdx.x * 128;           // l
    int n0 = blockIdx.y * 128;           // o (0..1535, 128-aligned -> t uniform per block)
    int tid = threadIdx.x;
    int lane = tid & 63, wid = tid >> 6;
    int quad = lane >> 4, n15 = lane & 15;
    const u16* Abase = xbt + ((size_t)b * L_ + m0) * 512;
    const u16* Bbase = wq + (size_t)n0 * 512;
    int mw = (wid & 1) * 64, nw = (wid >> 1) * 64;
    f32x4 acc[4][4] = {};
    for (int k0 = 0; k0 < 512; k0 += 64) {
        __syncthreads();
#pragma unroll
        for (int c = 0; c < 4; ++c) {
            int off = wid * 2048 + c * 512 + lane * 8;
            int row = off >> 6, col = off & 63;
            async16(Abase + (size_t)row * 512 + k0 + col, As + wid * 2048 + c * 512);
            async16(Bbase + (size_t)row * 512 + k0 + col, Bs + wid * 2048 + c * 512);
        }
        __syncthreads();
#pragma unroll
        for (int ks = 0; ks < 2; ++ks) {
            bf16x8 af[4], bfr[4];
#pragma unroll
            for (int i = 0; i < 4; ++i)
                af[i] = *(const bf16x8*)&As[(mw + i * 16 + n15) * 64 + ks * 32 + quad * 8];
#pragma unroll
            for (int j = 0; j < 4; ++j)
                bfr[j] = *(const bf16x8*)&Bs[(nw + j * 16 + n15) * 64 + ks * 32 + quad * 8];
#pragma unroll
            for (int i = 0; i < 4; ++i)
#pragma unroll
                for (int j = 0; j < 4; ++j)
                    acc[i][j] = mfma16(af[i], bfr[j], acc[i][j]);
        }
    }
    if (n0 < 512) {
        // Q: direct store [l][c], scaled by 0.125*LOG2E
#pragma unroll
        for (int i = 0; i < 4; ++i) {
#pragma unroll
            for (int j = 0; j < 4; ++j) {
                int o = n0 + nw + j * 16 + n15;
                int h = (o >> 6) & 7, cc = o & 63;
                u16* dst = qkv + ((size_t)b * 3 * 8 + h) * HSTRIDE + cc;
#pragma unroll
                for (int r = 0; r < 4; ++r) {
                    int l = m0 + mw + i * 16 + quad * 4 + r;
                    dst[(size_t)l * 64] = f2bf(acc[i][j][r] * (0.125f * LOG2E));
                }
            }
        }
    } else if (n0 < 1024) {
        // K: store in S^T-A-fragment order [tile][ks][quad_k][n15_k][j]
#pragma unroll
        for (int i = 0; i < 4; ++i) {
            int tile = (m0 + mw + i * 16) >> 4;       // block-uniform per i
#pragma unroll
            for (int j = 0; j < 4; ++j) {
                int o = n0 + nw + j * 16 + n15;
                int h = (o >> 6) & 7, c = o & 63;
                int ks_k = c >> 5, qk = (c >> 3) & 3, jj = c & 7;
                u16* dst = qkv + (((size_t)b * 3 + 1) * 8 + h) * HSTRIDE
                         + ((size_t)tile * 2 + ks_k) * 512 + qk * 128 + jj;
#pragma unroll
                for (int r = 0; r < 4; ++r) {
                    int n15k = quad * 4 + r;          // l & 15
                    dst[n15k * 8] = f2bf(acc[i][j][r]);
                }
            }
        }
    } else {
        // V: store directly in PV-B-fragment order (no LDS transpose, no barriers)
        // offset(l,c) = (l>>5)*2048 + (c>>4)*512 + ((l>>3)&3)*128 + (c&15)*8 + (l&7)
        int kt = m0 >> 7;
        u16* Vf = qkv + ((size_t)b * 3 + 2) * 8 * HSTRIDE;
#pragma unroll
        for (int i = 0; i < 4; ++i) {
            int L0 = mw + i * 16;
            int ks2 = (L0 >> 5) & 3;
            int r3 = ((L0 >> 3) + (quad >> 1)) & 3;
#pragma unroll
            for (int j = 0; j < 4; ++j) {
                int oo = (n0 - 1024) + nw + j * 16 + n15;
                int h = oo >> 6, c = oo & 63;
                ushort4 pk;
                pk.x = f2bf(acc[i][j][0]); pk.y = f2bf(acc[i][j][1]);
                pk.z = f2bf(acc[i][j][2]); pk.w = f2bf(acc[i][j][3]);
                *(ushort4*)&Vf[(size_t)h * HSTRIDE + kt * 8192 + ks2 * 2048
                               + (c >> 4) * 512 + r3 * 128 + n15 * 8 + (quad & 1) * 4] = pk;
            }
        }
    }
}

// ---------- kernel 2: attention, one block = (b,h) x 32 q-rows; WAVES SPLIT KEYS ----------
// R8 structure (additive key-split softmax, zero main-loop barriers, fragment-order
// K/V straight from global) with two occupancy levers:
//  - 32 q-rows/block (grid 2048): LDS 17.9 KB -> ~8 blocks/CU static ceiling
//    (R8's 35.8 KB + measured 21.7% occupancy starved the latency chain)
//  - P packed with one v_perm_b32 per pair (truncation; ratio O=sum(PV)/sum(P)
//    cancels the bias to first order) instead of 3-instr RNE per value.
__global__ __launch_bounds__(256, 4) void attn_kernel(const u16* __restrict__ qkv,
                                                      u16* __restrict__ o2) {
    __shared__ u16 Ps[4 * 32 * 68];      // 17408 B; reused as f32 reduction buffer
    __shared__ float Ls[4][32];          // per-wave row-sum partials
    int bh = blockIdx.y;
    int b = bh >> 3, h = bh & 7;
    int q0 = blockIdx.x * 32;
    int tid = threadIdx.x, lane = tid & 63, wid = tid >> 6;
    int quad = lane >> 4, n15 = lane & 15;
    const u16* Qp = qkv + (((size_t)b * 3 + 0) * 8 + h) * HSTRIDE;   // [l][c]
    const u16* Kf = qkv + (((size_t)b * 3 + 1) * 8 + h) * HSTRIDE;   // S^T-A frag order
    const u16* Vf = qkv + (((size_t)b * 3 + 2) * 8 + h) * HSTRIDE;   // PV-B frag order
    u16* Pw = Ps + wid * (32 * 68);      // wave-private P slice: 32 q x 64 keys

    // Q fragments (B-operand for S^T) for 32 q-rows, loaded once
    bf16x8 aq[2][2];
#pragma unroll
    for (int mf = 0; mf < 2; ++mf)
#pragma unroll
        for (int ks = 0; ks < 2; ++ks)
            aq[mf][ks] = *(const bf16x8*)
                &Qp[(size_t)(q0 + mf * 16 + n15) * 64 + ks * 32 + quad * 8];

    f32x4 oacc[2][4] = {};               // partial O over this wave's keys
    float lsumT[2] = {0.f, 0.f};

    // wave's key strip: [wid*512, wid*512+512), processed in 64-key chunks
    for (int it = 0; it < 8; ++it) {
        int tile0 = wid * 32 + it * 4;   // 16-key tile index
#pragma unroll
        for (int nf = 0; nf < 4; ++nf) {
            const u16* kb = Kf + (size_t)(tile0 + nf) * 1024;
            bf16x8 ak0 = *(const bf16x8*)&kb[lane * 8];
            bf16x8 ak1 = *(const bf16x8*)&kb[512 + lane * 8];
#pragma unroll
            for (int mf = 0; mf < 2; ++mf) {
                f32x4 sT = {};
                sT = mfma16(ak0, aq[mf][0], sT);
                sT = mfma16(ak1, aq[mf][1], sT);
                float p0 = __builtin_amdgcn_exp2f(sT[0]);
                float p1 = __builtin_amdgcn_exp2f(sT[1]);
                float p2 = __builtin_amdgcn_exp2f(sT[2]);
                float p3 = __builtin_amdgcn_exp2f(sT[3]);
                lsumT[mf] += (p0 + p1) + (p2 + p3);
                uint2 pw;
                pw.x = pk2(p0, p1);
                pw.y = pk2(p2, p3);
                *(uint2*)&Pw[(mf * 16 + n15) * 68 + nf * 16 + quad * 4] = pw;
            }
        }
        // O += P V for these 64 keys (two 32-key MFMA k-chunks)
#pragma unroll
        for (int sub = 0; sub < 2; ++sub) {
            bf16x8 pa[2];
#pragma unroll
            for (int mf = 0; mf < 2; ++mf)
                pa[mf] = *(const bf16x8*)&Pw[(mf * 16 + n15) * 68 + sub * 32 + quad * 8];
            const u16* vbb = Vf + (size_t)(wid * 16 + it * 2 + sub) * 2048;
#pragma unroll
            for (int nf2 = 0; nf2 < 4; ++nf2) {
                bf16x8 vb = *(const bf16x8*)&vbb[nf2 * 512 + lane * 8];
#pragma unroll
                for (int mf = 0; mf < 2; ++mf)
                    oacc[mf][nf2] = mfma16(pa[mf], vb, oacc[mf][nf2]);
            }
        }
    }

    // ---- cross-wave merge ----
#pragma unroll
    for (int mf = 0; mf < 2; ++mf) {
        float s = lsumT[mf];
        s += __shfl_xor(s, 16, 64);
        s += __shfl_xor(s, 32, 64);
        Ls[wid][mf * 16 + n15] = s;      // 4 quads write identical value: benign
    }
    float* Ored = (float*)Ps;            // [4 waves][16 rows x stride 68 f32]
#pragma unroll
    for (int mf = 0; mf < 2; ++mf) {
        __syncthreads();                 // mf=0: all waves done with P; else: prev read
        float* Od = Ored + wid * (16 * 68);
#pragma unroll
        for (int nf2 = 0; nf2 < 4; ++nf2)
#pragma unroll
            for (int r = 0; r < 4; ++r)
                Od[(quad * 4 + r) * 68 + nf2 * 16 + n15] = oacc[mf][nf2][r];
        __syncthreads();
        int row = tid >> 4, c0 = (tid & 15) * 4;
        float4 a0 = *(float4*)&Ored[0 * 1088 + row * 68 + c0];
        float4 a1 = *(float4*)&Ored[1 * 1088 + row * 68 + c0];
        float4 a2 = *(float4*)&Ored[2 * 1088 + row * 68 + c0];
        float4 a3 = *(float4*)&Ored[3 * 1088 + row * 68 + c0];
        float inv = 1.0f / (Ls[0][mf * 16 + row] + Ls[1][mf * 16 + row]
                          + Ls[2][mf * 16 + row] + Ls[3][mf * 16 + row]);
        ushort4 ov;
        ov.x = f2bf((a0.x + a1.x + a2.x + a3.x) * inv);
        ov.y = f2bf((a0.y + a1.y + a2.y + a3.y) * inv);
        ov.z = f2bf((a0.z + a1.z + a2.z + a3.z) * inv);
        ov.w = f2bf((a0.w + a1.w + a2.w + a3.w) * inv);
        *(ushort4*)&o2[((size_t)b * L_ + q0 + mf * 16 + row) * 512 + h * 64 + c0] = ov;
    }
}

// ---------- kernel 3: out GEMM  out[b,o,l] = sum_i w_out[o,i] o2[b,l,i] + b_out[o] ----------
__global__ __launch_bounds__(256, 2) void out_gemm(const u16* __restrict__ wo,
                                                   const u16* __restrict__ o2,
                                                   const float* __restrict__ bout,
                                                   float* __restrict__ out) {
    __shared__ u16 As[8192], Bs[8192];
    int b  = blockIdx.z;
    int m0 = blockIdx.y * 128;   // o
    int n0 = blockIdx.x * 128;   // l
    int tid = threadIdx.x, lane = tid & 63, wid = tid >> 6;
    int quad = lane >> 4, n15 = lane & 15;
    const u16* Abase = wo + (size_t)m0 * 512;
    const u16* Bbase = o2 + ((size_t)b * L_ + n0) * 512;
    int mw = (wid & 1) * 64, nw = (wid >> 1) * 64;
    f32x4 acc[4][4] = {};
    for (int k0 = 0; k0 < 512; k0 += 64) {
        __syncthreads();
#pragma unroll
        for (int c = 0; c < 4; ++c) {
            int off = wid * 2048 + c * 512 + lane * 8;
            int row = off >> 6, col = off & 63;
            async16(Abase + (size_t)row * 512 + k0 + col, As + wid * 2048 + c * 512);
            async16(Bbase + (size_t)row * 512 + k0 + col, Bs + wid * 2048 + c * 512);
        }
        __syncthreads();
#pragma unroll
        for (int ks = 0; ks < 2; ++ks) {
            bf16x8 af[4], bfr[4];
#pragma unroll
            for (int i = 0; i < 4; ++i)
                af[i] = *(const bf16x8*)&As[(mw + i * 16 + n15) * 64 + ks * 32 + quad * 8];
#pragma unroll
            for (int j = 0; j < 4; ++j)
                bfr[j] = *(const bf16x8*)&Bs[(nw + j * 16 + n15) * 64 + ks * 32 + quad * 8];
#pragma unroll
            for (int i = 0; i < 4; ++i)
#pragma unroll
                for (int j = 0; j < 4; ++j)
                    acc[i][j] = mfma16(af[i], bfr[j], acc[i][j]);
        }
    }
#pragma unroll
    for (int i = 0; i < 4; ++i) {
#pragma unroll
        for (int r = 0; r < 4; ++r) {
            int o_ = m0 + mw + i * 16 + quad * 4 + r;
            float bias = bout[o_];
            float* dst = out + ((size_t)b * 512 + o_) * L_ + n0;
#pragma unroll
            for (int j = 0; j < 4; ++j) dst[nw + j * 16 + n15] = acc[i][j][r] + bias;
        }
    }
}

// ---------- workspace layout (u16 elements) ----------
#define OFF_XBT  ((size_t)0)                            // 4*2048*512   = 4194304
#define OFF_WQKV (OFF_XBT + (size_t)B_ * L_ * 512)      // 1536*512     =  786432
#define OFF_WOUT (OFF_WQKV + (size_t)1536 * 512)        // 512*512      =  262144
#define OFF_QKV  (OFF_WOUT + (size_t)512 * 512)         // 3*4*8*2048*64= 12582912
#define OFF_O2   (OFF_QKV + (size_t)3 * B_ * 8 * L_ * 64)  // 4*2048*512

extern "C" void kernel_launch(void* const* d_in, const int* in_sizes, int n_in,
                              void* d_out, int out_size, void* d_ws, size_t ws_size,
                              hipStream_t stream) {
    (void)in_sizes; (void)n_in; (void)out_size; (void)ws_size;
    const float* x    = (const float*)d_in[0];
    const float* wqkv = (const float*)d_in[1];
    const float* wout = (const float*)d_in[2];
    const float* bout = (const float*)d_in[3];
    float* out = (float*)d_out;
    u16* ws = (u16*)d_ws;
    u16* xbt   = ws + OFF_XBT;
    u16* wqkvb = ws + OFF_WQKV;
    u16* woutb = ws + OFF_WOUT;
    u16* qkv   = ws + OFF_QKV;
    u16* o2    = ws + OFF_O2;

    convert_f32_bf16<<<768, 256, 0, stream>>>(wqkv, wqkvb, 1536 * 512);
    convert_f32_bf16<<<256, 256, 0, stream>>>(wout, woutb, 512 * 512);
    transpose_x<<<dim3(32, 8, 4), 256, 0, stream>>>(x, xbt);
    qkv_gemm<<<dim3(16, 12, 4), 256, 0, stream>>>(xbt, wqkvb, qkv);
    attn_kernel<<<dim3(64, 32), 256, 0, stream>>>(qkv, o2);
    out_gemm<<<dim3(16, 4, 4), 256, 0, stream>>>(woutb, o2, bout, out);
}

// Round 10
// 173.216 us; speedup vs baseline: 1.3639x; 1.0481x over previous
//
#include <hip/hip_runtime.h>

typedef unsigned short u16;
typedef __bf16 bf16x8 __attribute__((ext_vector_type(8)));
typedef float f32x4 __attribute__((ext_vector_type(4)));

#define B_ 4
#define L_ 2048
#define LOG2E 1.44269504088896340736f
#define HSTRIDE ((size_t)L_ * 64)   // one (b,t,h) plane: 2048*64 elements

// ---------- helpers ----------
__device__ __forceinline__ u16 f2bf(float f) {
    unsigned u = __float_as_uint(f);
    u += 0x7fff + ((u >> 16) & 1);   // RNE
    return (u16)(u >> 16);
}

// pack two f32 -> two bf16 (truncation) in ONE v_perm_b32
__device__ __forceinline__ unsigned pk2(float a, float b) {
    return __builtin_amdgcn_perm(__float_as_uint(b), __float_as_uint(a), 0x07060302u);
}

__device__ __forceinline__ f32x4 mfma16(bf16x8 a, bf16x8 b, f32x4 c) {
    return __builtin_amdgcn_mfma_f32_16x16x32_bf16(a, b, c, 0, 0, 0);
}

// async global->LDS, 16B per lane; LDS dest is wave-uniform base + lane*16
__device__ __forceinline__ void async16(const u16* g, u16* l) {
    __builtin_amdgcn_global_load_lds(
        (const __attribute__((address_space(1))) u16*)g,
        (__attribute__((address_space(3))) u16*)l, 16, 0, 0);
}

// ---------- kernel 0a: fp32 -> bf16 convert ----------
__global__ __launch_bounds__(256) void convert_f32_bf16(const float* __restrict__ in,
                                                        u16* __restrict__ out, int n) {
    int i = (blockIdx.x * 256 + threadIdx.x) * 4;
    if (i < n) {
        float4 f = *(const float4*)(in + i);
        ushort4 r;
        r.x = f2bf(f.x); r.y = f2bf(f.y); r.z = f2bf(f.z); r.w = f2bf(f.w);
        *(ushort4*)(out + i) = r;
    }
}

// ---------- kernel 0b: x[b][i][l] fp32 -> xbt[b][l][i] bf16 (64x64 LDS tiles) ----------
__global__ __launch_bounds__(256) void transpose_x(const float* __restrict__ x,
                                                   u16* __restrict__ xbt) {
    __shared__ u16 T[64][66];
    int b  = blockIdx.z;
    int i0 = blockIdx.y * 64;   // DIM tile (512/64 = 8)
    int l0 = blockIdx.x * 64;   // L tile  (2048/64 = 32)
    int t  = threadIdx.x;
    int c  = t & 63, r4 = t >> 6;
    const float* xb = x + ((size_t)b * 512 + i0) * 2048 + l0;
#pragma unroll
    for (int r = r4; r < 64; r += 4) T[r][c] = f2bf(xb[(size_t)r * 2048 + c]);
    __syncthreads();
    u16* ob = xbt + ((size_t)b * 2048 + l0) * 512 + i0;
#pragma unroll
    for (int r = r4; r < 64; r += 4) ob[(size_t)r * 512 + c] = T[c][r];
}

// ---------- kernel 1: QKV GEMM  qkv[b,o,l] = sum_i w[o,i] x[b,i,l] ----------
// m = l (128), n = o (128), K = 512, BK = 64.  A = xbt[b][l][i], B = w[o][i].
// Q stored [b][0][h][l][c], pre-scaled by 0.125*LOG2E (exp2-domain logits).
// K stored in MFMA-A(S^T)-fragment order: [b][1][h][tile(128)][ks(2)][quad][n15][j]
// V stored in MFMA-B(PV)-fragment order:  [b][2][h][chunk(64)][nf2(4)][lane][j]
// NEW (R10): Q and K epilogues go through an LDS transpose (T[l][o], stride 132,
// bank-conflict-free both directions) and store 16 B/lane fully coalesced —
// replaces 64 scalar 2-byte global stores/lane with 16x fewer line-writes.
__global__ __launch_bounds__(256, 2) void qkv_gemm(const u16* __restrict__ xbt,
                                                   const u16* __restrict__ wq,
                                                   u16* __restrict__ qkv) {
    __shared__ u16 smem[16896];          // As[0:8192], Bs[8192:16384]; epilogue T reuses all
    u16* As = smem;
    u16* Bs = smem + 8192;
    int b  = blockIdx.z;
    int m0 = blockIdx.x * 128;           // l
    int n0 = blockIdx.y * 128;           // o (0..1535, 128-aligned -> t uniform per block)
    int tid = threadIdx.x;
    int lane = tid & 63, wid = tid >> 6;
    int quad = lane >> 4, n15 = lane & 15;
    const u16* Abase = xbt + ((size_t)b * L_ + m0) * 512;
    const u16* Bbase = wq + (size_t)n0 * 512;
    int mw = (wid & 1) * 64, nw = (wid >> 1) * 64;
    f32x4 acc[4][4] = {};
    for (int k0 = 0; k0 < 512; k0 += 64) {
        __syncthreads();
#pragma unroll
        for (int c = 0; c < 4; ++c) {
            int off = wid * 2048 + c * 512 + lane * 8;
            int row = off >> 6, col = off & 63;
            async16(Abase + (size_t)row * 512 + k0 + col, As + wid * 2048 + c * 512);
            async16(Bbase + (size_t)row * 512 + k0 + col, Bs + wid * 2048 + c * 512);
        }
        __syncthreads();
#pragma unroll
        for (int ks = 0; ks < 2; ++ks) {
            bf16x8 af[4], bfr[4];
#pragma unroll
            for (int i = 0; i < 4; ++i)
                af[i] = *(const bf16x8*)&As[(mw + i * 16 + n15) * 64 + ks * 32 + quad * 8];
#pragma unroll
            for (int j = 0; j < 4; ++j)
                bfr[j] = *(const bf16x8*)&Bs[(nw + j * 16 + n15) * 64 + ks * 32 + quad * 8];
#pragma unroll
            for (int i = 0; i < 4; ++i)
#pragma unroll
                for (int j = 0; j < 4; ++j)
                    acc[i][j] = mfma16(af[i], bfr[j], acc[i][j]);
        }
    }
    if (n0 < 1024) {
        // Q or K: transpose through LDS T[l_loc][o_loc] (stride 132), then
        // coalesced 16 B/lane stores in the target layout.
        __syncthreads();
        u16* T = smem;
        float sc = (n0 < 512) ? (0.125f * LOG2E) : 1.0f;
#pragma unroll
        for (int i = 0; i < 4; ++i)
#pragma unroll
            for (int j = 0; j < 4; ++j)
#pragma unroll
                for (int r = 0; r < 4; ++r)
                    T[(mw + i * 16 + quad * 4 + r) * 132 + (nw + j * 16 + n15)] =
                        f2bf(acc[i][j][r] * sc);
        __syncthreads();
        int t = (n0 < 512) ? 0 : 1;
        int h0 = (n0 >> 6) & 7;
        u16* plane = qkv + (((size_t)b * 3 + t) * 8 + h0) * HSTRIDE + (size_t)m0 * 64;
#pragma unroll
        for (int it = 0; it < 8; ++it) {
            int flat = it * 2048 + tid * 8;
            int h_loc = flat >> 13;          // 0..1 (two heads per 128-o block)
            int remh = flat & 8191;          // within-head destination offset
            int src;
            if (t == 0) {
                // Q dest layout [l][c]: remh = l_loc*64 + cc
                int l_loc = remh >> 6, cc = remh & 63;
                src = l_loc * 132 + h_loc * 64 + cc;
            } else {
                // K dest layout [tile][ks][qk][n15k][jj]:
                // remh = tile_loc*1024 + ks*512 + qk*128 + n15k*8
                int tile_loc = remh >> 10;
                int remt = remh & 1023;
                int ks_ = remt >> 9, qk = (remt >> 7) & 3, n15k = (remt >> 3) & 15;
                src = (tile_loc * 16 + n15k) * 132 + h_loc * 64 + ks_ * 32 + qk * 8;
            }
            ushort4 lo = *(const ushort4*)&T[src];
            ushort4 hi = *(const ushort4*)&T[src + 4];
            u16* dst = plane + (size_t)h_loc * HSTRIDE + remh;
            *(ushort4*)dst = lo;
            *(ushort4*)(dst + 4) = hi;
        }
    } else {
        // V: store directly in PV-B-fragment order (proven R8/R9)
        // offset(l,c) = (l>>5)*2048 + (c>>4)*512 + ((l>>3)&3)*128 + (c&15)*8 + (l&7)
        int kt = m0 >> 7;
        u16* Vf = qkv + ((size_t)b * 3 + 2) * 8 * HSTRIDE;
#pragma unroll
        for (int i = 0; i < 4; ++i) {
            int L0 = mw + i * 16;
            int ks2 = (L0 >> 5) & 3;
            int r3 = ((L0 >> 3) + (quad >> 1)) & 3;
#pragma unroll
            for (int j = 0; j < 4; ++j) {
                int oo = (n0 - 1024) + nw + j * 16 + n15;
                int h = oo >> 6, c = oo & 63;
                ushort4 pk;
                pk.x = f2bf(acc[i][j][0]); pk.y = f2bf(acc[i][j][1]);
                pk.z = f2bf(acc[i][j][2]); pk.w = f2bf(acc[i][j][3]);
                *(ushort4*)&Vf[(size_t)h * HSTRIDE + kt * 8192 + ks2 * 2048
                               + (c >> 4) * 512 + r3 * 128 + n15 * 8 + (quad & 1) * 4] = pk;
            }
        }
    }
}

// ---------- kernel 2: attention, one block = (b,h) x 32 q-rows; WAVES SPLIT KEYS ----------
// R9 structure (proven 71.6 us) + row-sums computed by MFMA against a ones
// B-operand: sum lands in the SAME C-layout as O (row = quad*4+r), so the
// epilogue needs no shuffles and the main loop loses 24 VALU adds/it at the
// cost of 4 MFMA/it on a pipe with headroom. VGPR stays < 64 (8 waves/SIMD cap).
__global__ __launch_bounds__(256, 4) void attn_kernel(const u16* __restrict__ qkv,
                                                      u16* __restrict__ o2) {
    __shared__ u16 Ps[4 * 32 * 68];      // 17408 B; reused as f32 reduction buffer
    __shared__ float Ls[4][32];          // per-wave row-sum partials
    int bh = blockIdx.y;
    int b = bh >> 3, h = bh & 7;
    int q0 = blockIdx.x * 32;
    int tid = threadIdx.x, lane = tid & 63, wid = tid >> 6;
    int quad = lane >> 4, n15 = lane & 15;
    const u16* Qp = qkv + (((size_t)b * 3 + 0) * 8 + h) * HSTRIDE;   // [l][c]
    const u16* Kf = qkv + (((size_t)b * 3 + 1) * 8 + h) * HSTRIDE;   // S^T-A frag order
    const u16* Vf = qkv + (((size_t)b * 3 + 2) * 8 + h) * HSTRIDE;   // PV-B frag order
    u16* Pw = Ps + wid * (32 * 68);      // wave-private P slice: 32 q x 64 keys

    bf16x8 vones;
#pragma unroll
    for (int z = 0; z < 8; ++z) vones[z] = (__bf16)1.0f;

    // Q fragments (B-operand for S^T) for 32 q-rows, loaded once
    bf16x8 aq[2][2];
#pragma unroll
    for (int mf = 0; mf < 2; ++mf)
#pragma unroll
        for (int ks = 0; ks < 2; ++ks)
            aq[mf][ks] = *(const bf16x8*)
                &Qp[(size_t)(q0 + mf * 16 + n15) * 64 + ks * 32 + quad * 8];

    f32x4 oacc[2][4] = {};               // partial O over this wave's keys
    f32x4 osum[2] = {};                  // partial row sums (P x ones)

    // wave's key strip: [wid*512, wid*512+512), processed in 64-key chunks
    for (int it = 0; it < 8; ++it) {
        int tile0 = wid * 32 + it * 4;   // 16-key tile index
#pragma unroll
        for (int nf = 0; nf < 4; ++nf) {
            const u16* kb = Kf + (size_t)(tile0 + nf) * 1024;
            bf16x8 ak0 = *(const bf16x8*)&kb[lane * 8];
            bf16x8 ak1 = *(const bf16x8*)&kb[512 + lane * 8];
#pragma unroll
            for (int mf = 0; mf < 2; ++mf) {
                f32x4 sT = {};
                sT = mfma16(ak0, aq[mf][0], sT);
                sT = mfma16(ak1, aq[mf][1], sT);
                float p0 = __builtin_amdgcn_exp2f(sT[0]);
                float p1 = __builtin_amdgcn_exp2f(sT[1]);
                float p2 = __builtin_amdgcn_exp2f(sT[2]);
                float p3 = __builtin_amdgcn_exp2f(sT[3]);
                uint2 pw;
                pw.x = pk2(p0, p1);
                pw.y = pk2(p2, p3);
                *(uint2*)&Pw[(mf * 16 + n15) * 68 + nf * 16 + quad * 4] = pw;
            }
        }
        // O += P V ; rowsum += P x ones  (two 32-key MFMA k-chunks)
#pragma unroll
        for (int sub = 0; sub < 2; ++sub) {
            bf16x8 pa[2];
#pragma unroll
            for (int mf = 0; mf < 2; ++mf) {
                pa[mf] = *(const bf16x8*)&Pw[(mf * 16 + n15) * 68 + sub * 32 + quad * 8];
                osum[mf] = mfma16(pa[mf], vones, osum[mf]);
            }
            const u16* vbb = Vf + (size_t)(wid * 16 + it * 2 + sub) * 2048;
#pragma unroll
            for (int nf2 = 0; nf2 < 4; ++nf2) {
                bf16x8 vb = *(const bf16x8*)&vbb[nf2 * 512 + lane * 8];
#pragma unroll
                for (int mf = 0; mf < 2; ++mf)
                    oacc[mf][nf2] = mfma16(pa[mf], vb, oacc[mf][nf2]);
            }
        }
    }

    // ---- cross-wave merge ----
    // osum[mf][r] = rowsum for q-row mf*16+quad*4+r (identical across n15 lanes):
    // publish with the proven all-lanes-same-value LDS write; no shuffles needed.
#pragma unroll
    for (int mf = 0; mf < 2; ++mf)
#pragma unroll
        for (int r = 0; r < 4; ++r)
            Ls[wid][mf * 16 + quad * 4 + r] = osum[mf][r];
    float* Ored = (float*)Ps;            // [4 waves][16 rows x stride 68 f32]
#pragma unroll
    for (int mf = 0; mf < 2; ++mf) {
        __syncthreads();                 // mf=0: all waves done with P + Ls written
        float* Od = Ored + wid * (16 * 68);
#pragma unroll
        for (int nf2 = 0; nf2 < 4; ++nf2)
#pragma unroll
            for (int r = 0; r < 4; ++r)
                Od[(quad * 4 + r) * 68 + nf2 * 16 + n15] = oacc[mf][nf2][r];
        __syncthreads();
        int row = tid >> 4, c0 = (tid & 15) * 4;
        float4 a0 = *(float4*)&Ored[0 * 1088 + row * 68 + c0];
        float4 a1 = *(float4*)&Ored[1 * 1088 + row * 68 + c0];
        float4 a2 = *(float4*)&Ored[2 * 1088 + row * 68 + c0];
        float4 a3 = *(float4*)&Ored[3 * 1088 + row * 68 + c0];
        float inv = 1.0f / (Ls[0][mf * 16 + row] + Ls[1][mf * 16 + row]
                          + Ls[2][mf * 16 + row] + Ls[3][mf * 16 + row]);
        ushort4 ov;
        ov.x = f2bf((a0.x + a1.x + a2.x + a3.x) * inv);
        ov.y = f2bf((a0.y + a1.y + a2.y + a3.y) * inv);
        ov.z = f2bf((a0.z + a1.z + a2.z + a3.z) * inv);
        ov.w = f2bf((a0.w + a1.w + a2.w + a3.w) * inv);
        *(ushort4*)&o2[((size_t)b * L_ + q0 + mf * 16 + row) * 512 + h * 64 + c0] = ov;
    }
}

// ---------- kernel 3: out GEMM  out[b,o,l] = sum_i w_out[o,i] o2[b,l,i] + b_out[o] ----------
// R10: 64(o) x 128(l) tiles -> 512 blocks = 2 blocks/CU (was 256 = 1/CU).
__global__ __launch_bounds__(256, 2) void out_gemm(const u16* __restrict__ wo,
                                                   const u16* __restrict__ o2,
                                                   const float* __restrict__ bout,
                                                   float* __restrict__ out) {
    __shared__ u16 As[4096], Bs[8192];
    int b  = blockIdx.z;
    int m0 = blockIdx.y * 64;    // o
    int n0 = blockIdx.x * 128;   // l
    int tid = threadIdx.x, lane = tid & 63, wid = tid >> 6;
    int quad = lane >> 4, n15 = lane & 15;
    const u16* Abase = wo + (size_t)m0 * 512;
    const u16* Bbase = o2 + ((size_t)b * L_ + n0) * 512;
    int mw = (wid & 1) * 32, nw = (wid >> 1) * 64;
    f32x4 acc[2][4] = {};
    for (int k0 = 0; k0 < 512; k0 += 64) {
        __syncthreads();
#pragma unroll
        for (int a = 0; a < 2; ++a) {
            int off = wid * 1024 + a * 512 + lane * 8;
            int row = off >> 6, col = off & 63;
            async16(Abase + (size_t)row * 512 + k0 + col, As + off);
        }
#pragma unroll
        for (int c = 0; c < 4; ++c) {
            int off = wid * 2048 + c * 512 + lane * 8;
            int row = off >> 6, col = off & 63;
            async16(Bbase + (size_t)row * 512 + k0 + col, Bs + off);
        }
        __syncthreads();
#pragma unroll
        for (int ks = 0; ks < 2; ++ks) {
            bf16x8 af[2], bfr[4];
#pragma unroll
            for (int i = 0; i < 2; ++i)
                af[i] = *(const bf16x8*)&As[(mw + i * 16 + n15) * 64 + ks * 32 + quad * 8];
#pragma unroll
            for (int j = 0; j < 4; ++j)
                bfr[j] = *(const bf16x8*)&Bs[(nw + j * 16 + n15) * 64 + ks * 32 + quad * 8];
#pragma unroll
            for (int i = 0; i < 2; ++i)
#pragma unroll
                for (int j = 0; j < 4; ++j)
                    acc[i][j] = mfma16(af[i], bfr[j], acc[i][j]);
        }
    }
#pragma unroll
    for (int i = 0; i < 2; ++i) {
#pragma unroll
        for (int r = 0; r < 4; ++r) {
            int o_ = m0 + mw + i * 16 + quad * 4 + r;
            float bias = bout[o_];
            float* dst = out + ((size_t)b * 512 + o_) * L_ + n0;
#pragma unroll
            for (int j = 0; j < 4; ++j) dst[nw + j * 16 + n15] = acc[i][j][r] + bias;
        }
    }
}

// ---------- workspace layout (u16 elements) ----------
#define OFF_XBT  ((size_t)0)                            // 4*2048*512   = 4194304
#define OFF_WQKV (OFF_XBT + (size_t)B_ * L_ * 512)      // 1536*512     =  786432
#define OFF_WOUT (OFF_WQKV + (size_t)1536 * 512)        // 512*512      =  262144
#define OFF_QKV  (OFF_WOUT + (size_t)512 * 512)         // 3*4*8*2048*64= 12582912
#define OFF_O2   (OFF_QKV + (size_t)3 * B_ * 8 * L_ * 64)  // 4*2048*512

extern "C" void kernel_launch(void* const* d_in, const int* in_sizes, int n_in,
                              void* d_out, int out_size, void* d_ws, size_t ws_size,
                              hipStream_t stream) {
    (void)in_sizes; (void)n_in; (void)out_size; (void)ws_size;
    const float* x    = (const float*)d_in[0];
    const float* wqkv = (const float*)d_in[1];
    const float* wout = (const float*)d_in[2];
    const float* bout = (const float*)d_in[3];
    float* out = (float*)d_out;
    u16* ws = (u16*)d_ws;
    u16* xbt   = ws + OFF_XBT;
    u16* wqkvb = ws + OFF_WQKV;
    u16* woutb = ws + OFF_WOUT;
    u16* qkv   = ws + OFF_QKV;
    u16* o2    = ws + OFF_O2;

    convert_f32_bf16<<<768, 256, 0, stream>>>(wqkv, wqkvb, 1536 * 512);
    convert_f32_bf16<<<256, 256, 0, stream>>>(wout, woutb, 512 * 512);
    transpose_x<<<dim3(32, 8, 4), 256, 0, stream>>>(x, xbt);
    qkv_gemm<<<dim3(16, 12, 4), 256, 0, stream>>>(xbt, wqkvb, qkv);
    attn_kernel<<<dim3(64, 32), 256, 0, stream>>>(qkv, o2);
    out_gemm<<<dim3(16, 8, 4), 256, 0, stream>>>(woutb, o2, bout, out);
}

// Round 11
// 160.964 us; speedup vs baseline: 1.4677x; 1.0761x over previous
//
#include <hip/hip_runtime.h>

typedef unsigned short u16;
typedef __bf16 bf16x8 __attribute__((ext_vector_type(8)));
typedef float f32x4 __attribute__((ext_vector_type(4)));

#define B_ 4
#define L_ 2048
#define LOG2E 1.44269504088896340736f
#define HSTRIDE ((size_t)L_ * 64)   // one (b,t,h) plane: 2048*64 elements

// ---------- helpers ----------
__device__ __forceinline__ u16 f2bf(float f) {
    unsigned u = __float_as_uint(f);
    u += 0x7fff + ((u >> 16) & 1);   // RNE
    return (u16)(u >> 16);
}

// pack two f32 -> two bf16 (truncation) in ONE v_perm_b32
__device__ __forceinline__ unsigned pk2(float a, float b) {
    return __builtin_amdgcn_perm(__float_as_uint(b), __float_as_uint(a), 0x07060302u);
}

__device__ __forceinline__ f32x4 mfma16(bf16x8 a, bf16x8 b, f32x4 c) {
    return __builtin_amdgcn_mfma_f32_16x16x32_bf16(a, b, c, 0, 0, 0);
}

// async global->LDS, 16B per lane; LDS dest is wave-uniform base + lane*16
__device__ __forceinline__ void async16(const u16* g, u16* l) {
    __builtin_amdgcn_global_load_lds(
        (const __attribute__((address_space(1))) u16*)g,
        (__attribute__((address_space(3))) u16*)l, 16, 0, 0);
}

// ---------- kernel 0 (fused prep): converts + x-transpose in ONE launch ----------
// blocks [0,768): wqkv fp32->bf16 ; [768,1024): wout ; [1024,2048): transpose_x
__global__ __launch_bounds__(256) void prep_kernel(const float* __restrict__ x,
                                                   const float* __restrict__ wqkv,
                                                   const float* __restrict__ wout,
                                                   u16* __restrict__ xbt,
                                                   u16* __restrict__ wqkvb,
                                                   u16* __restrict__ woutb) {
    __shared__ u16 T[64][66];
    int bid = blockIdx.x;
    if (bid < 1024) {
        const float* in = (bid < 768) ? wqkv : wout;
        u16* out = (bid < 768) ? wqkvb : woutb;
        int blk = (bid < 768) ? bid : (bid - 768);
        int i = (blk * 256 + threadIdx.x) * 4;
        float4 f = *(const float4*)(in + i);
        ushort4 r;
        r.x = f2bf(f.x); r.y = f2bf(f.y); r.z = f2bf(f.z); r.w = f2bf(f.w);
        *(ushort4*)(out + i) = r;
    } else {
        int t0 = bid - 1024;                 // 0..1023 = (l0:32, i0:8, b:4)
        int b  = t0 >> 8;
        int i0 = ((t0 >> 5) & 7) * 64;
        int l0 = (t0 & 31) * 64;
        int t  = threadIdx.x;
        int c  = t & 63, r4 = t >> 6;
        const float* xb = x + ((size_t)b * 512 + i0) * 2048 + l0;
#pragma unroll
        for (int r = r4; r < 64; r += 4) T[r][c] = f2bf(xb[(size_t)r * 2048 + c]);
        __syncthreads();
        u16* ob = xbt + ((size_t)b * 2048 + l0) * 512 + i0;
#pragma unroll
        for (int r = r4; r < 64; r += 4) ob[(size_t)r * 512 + c] = T[c][r];
    }
}

// ---------- kernel 1: QKV GEMM  qkv[b,o,l] = sum_i w[o,i] x[b,i,l] ----------
// m = l (128), n = o (128), K = 512, BK = 64.  A = xbt[b][l][i], B = w[o][i].
// Q stored [b][0][h][l][c], pre-scaled by 0.125*LOG2E (exp2-domain logits).
// K stored in MFMA-A(S^T)-fragment order: [b][1][h][tile(128)][ks(2)][quad][n15][j]
// V stored in MFMA-B(PV)-fragment order:  [b][2][h][chunk(64)][nf2(4)][lane][j]
// Q/K epilogues via LDS transpose (stride 132) -> coalesced 16 B/lane stores.
__global__ __launch_bounds__(256, 2) void qkv_gemm(const u16* __restrict__ xbt,
                                                   const u16* __restrict__ wq,
                                                   u16* __restrict__ qkv) {
    __shared__ u16 smem[16896];          // As[0:8192], Bs[8192:16384]; epilogue T reuses all
    u16* As = smem;
    u16* Bs = smem + 8192;
    int b  = blockIdx.z;
    int m0 = blockIdx.x * 128;           // l
    int n0 = blockIdx.y * 128;           // o (0..1535, 128-aligned -> t uniform per block)
    int tid = threadIdx.x;
    int lane = tid & 63, wid = tid >> 6;
    int quad = lane >> 4, n15 = lane & 15;
    const u16* Abase = xbt + ((size_t)b * L_ + m0) * 512;
    const u16* Bbase = wq + (size_t)n0 * 512;
    int mw = (wid & 1) * 64, nw = (wid >> 1) * 64;
    f32x4 acc[4][4] = {};
    for (int k0 = 0; k0 < 512; k0 += 64) {
        __syncthreads();
#pragma unroll
        for (int c = 0; c < 4; ++c) {
            int off = wid * 2048 + c * 512 + lane * 8;
            int row = off >> 6, col = off & 63;
            async16(Abase + (size_t)row * 512 + k0 + col, As + wid * 2048 + c * 512);
            async16(Bbase + (size_t)row * 512 + k0 + col, Bs + wid * 2048 + c * 512);
        }
        __syncthreads();
#pragma unroll
        for (int ks = 0; ks < 2; ++ks) {
            bf16x8 af[4], bfr[4];
#pragma unroll
            for (int i = 0; i < 4; ++i)
                af[i] = *(const bf16x8*)&As[(mw + i * 16 + n15) * 64 + ks * 32 + quad * 8];
#pragma unroll
            for (int j = 0; j < 4; ++j)
                bfr[j] = *(const bf16x8*)&Bs[(nw + j * 16 + n15) * 64 + ks * 32 + quad * 8];
#pragma unroll
            for (int i = 0; i < 4; ++i)
#pragma unroll
                for (int j = 0; j < 4; ++j)
                    acc[i][j] = mfma16(af[i], bfr[j], acc[i][j]);
        }
    }
    if (n0 < 1024) {
        // Q or K: transpose through LDS T[l_loc][o_loc] (stride 132), then
        // coalesced 16 B/lane stores in the target layout.
        __syncthreads();
        u16* T = smem;
        float sc = (n0 < 512) ? (0.125f * LOG2E) : 1.0f;
#pragma unroll
        for (int i = 0; i < 4; ++i)
#pragma unroll
            for (int j = 0; j < 4; ++j)
#pragma unroll
                for (int r = 0; r < 4; ++r)
                    T[(mw + i * 16 + quad * 4 + r) * 132 + (nw + j * 16 + n15)] =
                        f2bf(acc[i][j][r] * sc);
        __syncthreads();
        int t = (n0 < 512) ? 0 : 1;
        int h0 = (n0 >> 6) & 7;
        u16* plane = qkv + (((size_t)b * 3 + t) * 8 + h0) * HSTRIDE + (size_t)m0 * 64;
#pragma unroll
        for (int it = 0; it < 8; ++it) {
            int flat = it * 2048 + tid * 8;
            int h_loc = flat >> 13;          // 0..1 (two heads per 128-o block)
            int remh = flat & 8191;          // within-head destination offset
            int src;
            if (t == 0) {
                int l_loc = remh >> 6, cc = remh & 63;
                src = l_loc * 132 + h_loc * 64 + cc;
            } else {
                int tile_loc = remh >> 10;
                int remt = remh & 1023;
                int ks_ = remt >> 9, qk = (remt >> 7) & 3, n15k = (remt >> 3) & 15;
                src = (tile_loc * 16 + n15k) * 132 + h_loc * 64 + ks_ * 32 + qk * 8;
            }
            ushort4 lo = *(const ushort4*)&T[src];
            ushort4 hi = *(const ushort4*)&T[src + 4];
            u16* dst = plane + (size_t)h_loc * HSTRIDE + remh;
            *(ushort4*)dst = lo;
            *(ushort4*)(dst + 4) = hi;
        }
    } else {
        // V: store directly in PV-B-fragment order (proven R8/R9)
        int kt = m0 >> 7;
        u16* Vf = qkv + ((size_t)b * 3 + 2) * 8 * HSTRIDE;
#pragma unroll
        for (int i = 0; i < 4; ++i) {
            int L0 = mw + i * 16;
            int ks2 = (L0 >> 5) & 3;
            int r3 = ((L0 >> 3) + (quad >> 1)) & 3;
#pragma unroll
            for (int j = 0; j < 4; ++j) {
                int oo = (n0 - 1024) + nw + j * 16 + n15;
                int h = oo >> 6, c = oo & 63;
                ushort4 pk;
                pk.x = f2bf(acc[i][j][0]); pk.y = f2bf(acc[i][j][1]);
                pk.z = f2bf(acc[i][j][2]); pk.w = f2bf(acc[i][j][3]);
                *(ushort4*)&Vf[(size_t)h * HSTRIDE + kt * 8192 + ks2 * 2048
                               + (c >> 4) * 512 + r3 * 128 + n15 * 8 + (quad & 1) * 4] = pk;
            }
        }
    }
}

// ---------- kernel 2: attention, one block = (b,h) x 32 q-rows; WAVES SPLIT KEYS ----------
// R10 structure + EXPLICIT REGISTER PIPELINE (R10 counters: MFMA 22% + VALU 22%
// busy, ~55% idle = exposed K/V load latency; compiler at VGPR=56 refused to
// hoist loads across phases). K and V fragments live in registers; next-iter
// loads are issued where they get a full phase of latency cover:
//   K(it+1) right after S(it) consumes kf  (cover: PV + S-write, ~400 cyc)
//   V(it+1) right after PV(it) consumes vf (cover: S(it+1), ~300 cyc)
// Single-buffered (+64 VGPR, ~3 waves/SIMD = same occupancy as measured 39%).
__global__ __launch_bounds__(256, 4) void attn_kernel(const u16* __restrict__ qkv,
                                                      u16* __restrict__ o2) {
    __shared__ u16 Ps[4 * 32 * 68];      // 17408 B; reused as f32 reduction buffer
    __shared__ float Ls[4][32];          // per-wave row-sum partials
    int bh = blockIdx.y;
    int b = bh >> 3, h = bh & 7;
    int q0 = blockIdx.x * 32;
    int tid = threadIdx.x, lane = tid & 63, wid = tid >> 6;
    int quad = lane >> 4, n15 = lane & 15;
    const u16* Qp = qkv + (((size_t)b * 3 + 0) * 8 + h) * HSTRIDE;   // [l][c]
    const u16* Kf = qkv + (((size_t)b * 3 + 1) * 8 + h) * HSTRIDE;   // S^T-A frag order
    const u16* Vf = qkv + (((size_t)b * 3 + 2) * 8 + h) * HSTRIDE;   // PV-B frag order
    u16* Pw = Ps + wid * (32 * 68);      // wave-private P slice: 32 q x 64 keys

    bf16x8 vones;
#pragma unroll
    for (int z = 0; z < 8; ++z) vones[z] = (__bf16)1.0f;

    // Q fragments (B-operand for S^T) for 32 q-rows, loaded once
    bf16x8 aq[2][2];
#pragma unroll
    for (int mf = 0; mf < 2; ++mf)
#pragma unroll
        for (int ks = 0; ks < 2; ++ks)
            aq[mf][ks] = *(const bf16x8*)
                &Qp[(size_t)(q0 + mf * 16 + n15) * 64 + ks * 32 + quad * 8];

    f32x4 oacc[2][4] = {};               // partial O over this wave's keys
    f32x4 osum[2] = {};                  // partial row sums (P x ones)

    // register-resident K/V fragments for the CURRENT iteration
    bf16x8 kf[4][2], vf[2][4];
    {
        int tile0 = wid * 32;
#pragma unroll
        for (int nf = 0; nf < 4; ++nf) {
            const u16* kb = Kf + (size_t)(tile0 + nf) * 1024;
            kf[nf][0] = *(const bf16x8*)&kb[lane * 8];
            kf[nf][1] = *(const bf16x8*)&kb[512 + lane * 8];
        }
#pragma unroll
        for (int sub = 0; sub < 2; ++sub) {
            const u16* vbb = Vf + (size_t)(wid * 16 + sub) * 2048;
#pragma unroll
            for (int nf2 = 0; nf2 < 4; ++nf2)
                vf[sub][nf2] = *(const bf16x8*)&vbb[nf2 * 512 + lane * 8];
        }
    }

    // wave's key strip: [wid*512, wid*512+512), processed in 64-key chunks
#pragma unroll
    for (int it = 0; it < 8; ++it) {
        // ---- S phase: uses kf (already in registers; no VMEM wait) ----
#pragma unroll
        for (int nf = 0; nf < 4; ++nf) {
#pragma unroll
            for (int mf = 0; mf < 2; ++mf) {
                f32x4 sT = {};
                sT = mfma16(kf[nf][0], aq[mf][0], sT);
                sT = mfma16(kf[nf][1], aq[mf][1], sT);
                float p0 = __builtin_amdgcn_exp2f(sT[0]);
                float p1 = __builtin_amdgcn_exp2f(sT[1]);
                float p2 = __builtin_amdgcn_exp2f(sT[2]);
                float p3 = __builtin_amdgcn_exp2f(sT[3]);
                uint2 pw;
                pw.x = pk2(p0, p1);
                pw.y = pk2(p2, p3);
                *(uint2*)&Pw[(mf * 16 + n15) * 68 + nf * 16 + quad * 4] = pw;
            }
        }
        // ---- prefetch K(it+1): kf is dead; cover = PV(it) + S-write(it+1) ----
        if (it < 7) {
            int tile0 = wid * 32 + (it + 1) * 4;
#pragma unroll
            for (int nf = 0; nf < 4; ++nf) {
                const u16* kb = Kf + (size_t)(tile0 + nf) * 1024;
                kf[nf][0] = *(const bf16x8*)&kb[lane * 8];
                kf[nf][1] = *(const bf16x8*)&kb[512 + lane * 8];
            }
        }
        // ---- PV phase: uses vf (in registers) + P from wave-private LDS ----
#pragma unroll
        for (int sub = 0; sub < 2; ++sub) {
            bf16x8 pa[2];
#pragma unroll
            for (int mf = 0; mf < 2; ++mf) {
                pa[mf] = *(const bf16x8*)&Pw[(mf * 16 + n15) * 68 + sub * 32 + quad * 8];
                osum[mf] = mfma16(pa[mf], vones, osum[mf]);
            }
#pragma unroll
            for (int nf2 = 0; nf2 < 4; ++nf2)
#pragma unroll
                for (int mf = 0; mf < 2; ++mf)
                    oacc[mf][nf2] = mfma16(pa[mf], vf[sub][nf2], oacc[mf][nf2]);
        }
        // ---- prefetch V(it+1): vf is dead; cover = S(it+1) ----
        if (it < 7) {
#pragma unroll
            for (int sub = 0; sub < 2; ++sub) {
                const u16* vbb = Vf + (size_t)(wid * 16 + (it + 1) * 2 + sub) * 2048;
#pragma unroll
                for (int nf2 = 0; nf2 < 4; ++nf2)
                    vf[sub][nf2] = *(const bf16x8*)&vbb[nf2 * 512 + lane * 8];
            }
        }
    }

    // ---- cross-wave merge ----
    // osum[mf][r] = rowsum for q-row mf*16+quad*4+r (identical across n15 lanes)
#pragma unroll
    for (int mf = 0; mf < 2; ++mf)
#pragma unroll
        for (int r = 0; r < 4; ++r)
            Ls[wid][mf * 16 + quad * 4 + r] = osum[mf][r];
    float* Ored = (float*)Ps;            // [4 waves][16 rows x stride 68 f32]
#pragma unroll
    for (int mf = 0; mf < 2; ++mf) {
        __syncthreads();                 // mf=0: all waves done with P + Ls written
        float* Od = Ored + wid * (16 * 68);
#pragma unroll
        for (int nf2 = 0; nf2 < 4; ++nf2)
#pragma unroll
            for (int r = 0; r < 4; ++r)
                Od[(quad * 4 + r) * 68 + nf2 * 16 + n15] = oacc[mf][nf2][r];
        __syncthreads();
        int row = tid >> 4, c0 = (tid & 15) * 4;
        float4 a0 = *(float4*)&Ored[0 * 1088 + row * 68 + c0];
        float4 a1 = *(float4*)&Ored[1 * 1088 + row * 68 + c0];
        float4 a2 = *(float4*)&Ored[2 * 1088 + row * 68 + c0];
        float4 a3 = *(float4*)&Ored[3 * 1088 + row * 68 + c0];
        float inv = 1.0f / (Ls[0][mf * 16 + row] + Ls[1][mf * 16 + row]
                          + Ls[2][mf * 16 + row] + Ls[3][mf * 16 + row]);
        ushort4 ov;
        ov.x = f2bf((a0.x + a1.x + a2.x + a3.x) * inv);
        ov.y = f2bf((a0.y + a1.y + a2.y + a3.y) * inv);
        ov.z = f2bf((a0.z + a1.z + a2.z + a3.z) * inv);
        ov.w = f2bf((a0.w + a1.w + a2.w + a3.w) * inv);
        *(ushort4*)&o2[((size_t)b * L_ + q0 + mf * 16 + row) * 512 + h * 64 + c0] = ov;
    }
}

// ---------- kernel 3: out GEMM  out[b,o,l] = sum_i w_out[o,i] o2[b,l,i] + b_out[o] ----------
// 64(o) x 128(l) tiles -> 512 blocks = 2 blocks/CU.
__global__ __launch_bounds__(256, 2) void out_gemm(const u16* __restrict__ wo,
                                                   const u16* __restrict__ o2,
                                                   const float* __restrict__ bout,
                                                   float* __restrict__ out) {
    __shared__ u16 As[4096], Bs[8192];
    int b  = blockIdx.z;
    int m0 = blockIdx.y * 64;    // o
    int n0 = blockIdx.x * 128;   // l
    int tid = threadIdx.x, lane = tid & 63, wid = tid >> 6;
    int quad = lane >> 4, n15 = lane & 15;
    const u16* Abase = wo + (size_t)m0 * 512;
    const u16* Bbase = o2 + ((size_t)b * L_ + n0) * 512;
    int mw = (wid & 1) * 32, nw = (wid >> 1) * 64;
    f32x4 acc[2][4] = {};
    for (int k0 = 0; k0 < 512; k0 += 64) {
        __syncthreads();
#pragma unroll
        for (int a = 0; a < 2; ++a) {
            int off = wid * 1024 + a * 512 + lane * 8;
            int row = off >> 6, col = off & 63;
            async16(Abase + (size_t)row * 512 + k0 + col, As + off);
        }
#pragma unroll
        for (int c = 0; c < 4; ++c) {
            int off = wid * 2048 + c * 512 + lane * 8;
            int row = off >> 6, col = off & 63;
            async16(Bbase + (size_t)row * 512 + k0 + col, Bs + off);
        }
        __syncthreads();
#pragma unroll
        for (int ks = 0; ks < 2; ++ks) {
            bf16x8 af[2], bfr[4];
#pragma unroll
            for (int i = 0; i < 2; ++i)
                af[i] = *(const bf16x8*)&As[(mw + i * 16 + n15) * 64 + ks * 32 + quad * 8];
#pragma unroll
            for (int j = 0; j < 4; ++j)
                bfr[j] = *(const bf16x8*)&Bs[(nw + j * 16 + n15) * 64 + ks * 32 + quad * 8];
#pragma unroll
            for (int i = 0; i < 2; ++i)
#pragma unroll
                for (int j = 0; j < 4; ++j)
                    acc[i][j] = mfma16(af[i], bfr[j], acc[i][j]);
        }
    }
#pragma unroll
    for (int i = 0; i < 2; ++i) {
#pragma unroll
        for (int r = 0; r < 4; ++r) {
            int o_ = m0 + mw + i * 16 + quad * 4 + r;
            float bias = bout[o_];
            float* dst = out + ((size_t)b * 512 + o_) * L_ + n0;
#pragma unroll
            for (int j = 0; j < 4; ++j) dst[nw + j * 16 + n15] = acc[i][j][r] + bias;
        }
    }
}

// ---------- workspace layout (u16 elements) ----------
#define OFF_XBT  ((size_t)0)                            // 4*2048*512   = 4194304
#define OFF_WQKV (OFF_XBT + (size_t)B_ * L_ * 512)      // 1536*512     =  786432
#define OFF_WOUT (OFF_WQKV + (size_t)1536 * 512)        // 512*512      =  262144
#define OFF_QKV  (OFF_WOUT + (size_t)512 * 512)         // 3*4*8*2048*64= 12582912
#define OFF_O2   (OFF_QKV + (size_t)3 * B_ * 8 * L_ * 64)  // 4*2048*512

extern "C" void kernel_launch(void* const* d_in, const int* in_sizes, int n_in,
                              void* d_out, int out_size, void* d_ws, size_t ws_size,
                              hipStream_t stream) {
    (void)in_sizes; (void)n_in; (void)out_size; (void)ws_size;
    const float* x    = (const float*)d_in[0];
    const float* wqkv = (const float*)d_in[1];
    const float* wout = (const float*)d_in[2];
    const float* bout = (const float*)d_in[3];
    float* out = (float*)d_out;
    u16* ws = (u16*)d_ws;
    u16* xbt   = ws + OFF_XBT;
    u16* wqkvb = ws + OFF_WQKV;
    u16* woutb = ws + OFF_WOUT;
    u16* qkv   = ws + OFF_QKV;
    u16* o2    = ws + OFF_O2;

    prep_kernel<<<2048, 256, 0, stream>>>(x, wqkv, wout, xbt, wqkvb, woutb);
    qkv_gemm<<<dim3(16, 12, 4), 256, 0, stream>>>(xbt, wqkvb, qkv);
    attn_kernel<<<dim3(64, 32), 256, 0, stream>>>(qkv, o2);
    out_gemm<<<dim3(16, 8, 4), 256, 0, stream>>>(woutb, o2, bout, out);
}

// Round 12
// 155.613 us; speedup vs baseline: 1.5181x; 1.0344x over previous
//
#include <hip/hip_runtime.h>

typedef unsigned short u16;
typedef __bf16 bf16x8 __attribute__((ext_vector_type(8)));
typedef float f32x4 __attribute__((ext_vector_type(4)));

#define B_ 4
#define L_ 2048
#define LOG2E 1.44269504088896340736f
#define HSTRIDE ((size_t)L_ * 64)   // one (b,t,h) plane: 2048*64 elements

// ---------- helpers ----------
__device__ __forceinline__ u16 f2bf(float f) {
    unsigned u = __float_as_uint(f);
    u += 0x7fff + ((u >> 16) & 1);   // RNE
    return (u16)(u >> 16);
}

// pack two f32 -> two bf16 (truncation) in ONE v_perm_b32
__device__ __forceinline__ unsigned pk2(float a, float b) {
    return __builtin_amdgcn_perm(__float_as_uint(b), __float_as_uint(a), 0x07060302u);
}

__device__ __forceinline__ f32x4 mfma16(bf16x8 a, bf16x8 b, f32x4 c) {
    return __builtin_amdgcn_mfma_f32_16x16x32_bf16(a, b, c, 0, 0, 0);
}

// async global->LDS, 16B per lane; LDS dest is wave-uniform base + lane*16
__device__ __forceinline__ void async16(const u16* g, u16* l) {
    __builtin_amdgcn_global_load_lds(
        (const __attribute__((address_space(1))) u16*)g,
        (__attribute__((address_space(3))) u16*)l, 16, 0, 0);
}

// ---------- kernel 0 (fused prep): converts + x-transpose in ONE launch ----------
// blocks [0,768): wqkv fp32->bf16 ; [768,1024): wout ; [1024,2048): transpose_x
__global__ __launch_bounds__(256) void prep_kernel(const float* __restrict__ x,
                                                   const float* __restrict__ wqkv,
                                                   const float* __restrict__ wout,
                                                   u16* __restrict__ xbt,
                                                   u16* __restrict__ wqkvb,
                                                   u16* __restrict__ woutb) {
    __shared__ u16 T[64][66];
    int bid = blockIdx.x;
    if (bid < 1024) {
        const float* in = (bid < 768) ? wqkv : wout;
        u16* out = (bid < 768) ? wqkvb : woutb;
        int blk = (bid < 768) ? bid : (bid - 768);
        int i = (blk * 256 + threadIdx.x) * 4;
        float4 f = *(const float4*)(in + i);
        ushort4 r;
        r.x = f2bf(f.x); r.y = f2bf(f.y); r.z = f2bf(f.z); r.w = f2bf(f.w);
        *(ushort4*)(out + i) = r;
    } else {
        int t0 = bid - 1024;                 // 0..1023 = (l0:32, i0:8, b:4)
        int b  = t0 >> 8;
        int i0 = ((t0 >> 5) & 7) * 64;
        int l0 = (t0 & 31) * 64;
        int t  = threadIdx.x;
        int c  = t & 63, r4 = t >> 6;
        const float* xb = x + ((size_t)b * 512 + i0) * 2048 + l0;
#pragma unroll
        for (int r = r4; r < 64; r += 4) T[r][c] = f2bf(xb[(size_t)r * 2048 + c]);
        __syncthreads();
        u16* ob = xbt + ((size_t)b * 2048 + l0) * 512 + i0;
#pragma unroll
        for (int r = r4; r < 64; r += 4) ob[(size_t)r * 512 + c] = T[c][r];
    }
}

// ---------- kernel 1: QKV GEMM  qkv[b,o,l] = sum_i w[o,i] x[b,i,l] ----------
// m = l (128), n = o (128), K = 512, BK = 64.  A = xbt[b][l][i], B = w[o][i].
// Q stored [b][0][h][l][c], pre-scaled by 0.125*LOG2E (exp2-domain logits).
// K stored in MFMA-A(S^T)-fragment order: [b][1][h][tile(128)][ks(2)][quad][n15][j]
// V stored in MFMA-B(PV)-fragment order:  [b][2][h][chunk(64)][nf2(4)][lane][j]
// Q/K epilogues via LDS transpose (stride 132) -> coalesced 16 B/lane stores.
__global__ __launch_bounds__(256, 2) void qkv_gemm(const u16* __restrict__ xbt,
                                                   const u16* __restrict__ wq,
                                                   u16* __restrict__ qkv) {
    __shared__ u16 smem[16896];          // As[0:8192], Bs[8192:16384]; epilogue T reuses all
    u16* As = smem;
    u16* Bs = smem + 8192;
    int b  = blockIdx.z;
    int m0 = blockIdx.x * 128;           // l
    int n0 = blockIdx.y * 128;           // o (0..1535, 128-aligned -> t uniform per block)
    int tid = threadIdx.x;
    int lane = tid & 63, wid = tid >> 6;
    int quad = lane >> 4, n15 = lane & 15;
    const u16* Abase = xbt + ((size_t)b * L_ + m0) * 512;
    const u16* Bbase = wq + (size_t)n0 * 512;
    int mw = (wid & 1) * 64, nw = (wid >> 1) * 64;
    f32x4 acc[4][4] = {};
    for (int k0 = 0; k0 < 512; k0 += 64) {
        __syncthreads();
#pragma unroll
        for (int c = 0; c < 4; ++c) {
            int off = wid * 2048 + c * 512 + lane * 8;
            int row = off >> 6, col = off & 63;
            async16(Abase + (size_t)row * 512 + k0 + col, As + wid * 2048 + c * 512);
            async16(Bbase + (size_t)row * 512 + k0 + col, Bs + wid * 2048 + c * 512);
        }
        __syncthreads();
#pragma unroll
        for (int ks = 0; ks < 2; ++ks) {
            bf16x8 af[4], bfr[4];
#pragma unroll
            for (int i = 0; i < 4; ++i)
                af[i] = *(const bf16x8*)&As[(mw + i * 16 + n15) * 64 + ks * 32 + quad * 8];
#pragma unroll
            for (int j = 0; j < 4; ++j)
                bfr[j] = *(const bf16x8*)&Bs[(nw + j * 16 + n15) * 64 + ks * 32 + quad * 8];
#pragma unroll
            for (int i = 0; i < 4; ++i)
#pragma unroll
                for (int j = 0; j < 4; ++j)
                    acc[i][j] = mfma16(af[i], bfr[j], acc[i][j]);
        }
    }
    if (n0 < 1024) {
        // Q or K: transpose through LDS T[l_loc][o_loc] (stride 132), then
        // coalesced 16 B/lane stores in the target layout.
        __syncthreads();
        u16* T = smem;
        float sc = (n0 < 512) ? (0.125f * LOG2E) : 1.0f;
#pragma unroll
        for (int i = 0; i < 4; ++i)
#pragma unroll
            for (int j = 0; j < 4; ++j)
#pragma unroll
                for (int r = 0; r < 4; ++r)
                    T[(mw + i * 16 + quad * 4 + r) * 132 + (nw + j * 16 + n15)] =
                        f2bf(acc[i][j][r] * sc);
        __syncthreads();
        int t = (n0 < 512) ? 0 : 1;
        int h0 = (n0 >> 6) & 7;
        u16* plane = qkv + (((size_t)b * 3 + t) * 8 + h0) * HSTRIDE + (size_t)m0 * 64;
#pragma unroll
        for (int it = 0; it < 8; ++it) {
            int flat = it * 2048 + tid * 8;
            int h_loc = flat >> 13;          // 0..1 (two heads per 128-o block)
            int remh = flat & 8191;          // within-head destination offset
            int src;
            if (t == 0) {
                int l_loc = remh >> 6, cc = remh & 63;
                src = l_loc * 132 + h_loc * 64 + cc;
            } else {
                int tile_loc = remh >> 10;
                int remt = remh & 1023;
                int ks_ = remt >> 9, qk = (remt >> 7) & 3, n15k = (remt >> 3) & 15;
                src = (tile_loc * 16 + n15k) * 132 + h_loc * 64 + ks_ * 32 + qk * 8;
            }
            ushort4 lo = *(const ushort4*)&T[src];
            ushort4 hi = *(const ushort4*)&T[src + 4];
            u16* dst = plane + (size_t)h_loc * HSTRIDE + remh;
            *(ushort4*)dst = lo;
            *(ushort4*)(dst + 4) = hi;
        }
    } else {
        // V: store directly in PV-B-fragment order (proven R8/R9)
        int kt = m0 >> 7;
        u16* Vf = qkv + ((size_t)b * 3 + 2) * 8 * HSTRIDE;
#pragma unroll
        for (int i = 0; i < 4; ++i) {
            int L0 = mw + i * 16;
            int ks2 = (L0 >> 5) & 3;
            int r3 = ((L0 >> 3) + (quad >> 1)) & 3;
#pragma unroll
            for (int j = 0; j < 4; ++j) {
                int oo = (n0 - 1024) + nw + j * 16 + n15;
                int h = oo >> 6, c = oo & 63;
                ushort4 pk;
                pk.x = f2bf(acc[i][j][0]); pk.y = f2bf(acc[i][j][1]);
                pk.z = f2bf(acc[i][j][2]); pk.w = f2bf(acc[i][j][3]);
                *(ushort4*)&Vf[(size_t)h * HSTRIDE + kt * 8192 + ks2 * 2048
                               + (c >> 4) * 512 + r3 * 128 + n15 * 8 + (quad & 1) * 4] = pk;
            }
        }
    }
}

// ---------- kernel 2: attention, one block = (b,h) x 64 q-rows; WAVES SPLIT KEYS ----------
// R11 structure scaled to 64 q-rows/block: K/V L2->L1 traffic halves (1 GB ->
// 512 MB total; was ~50% of chip L2 peak). Pays VGPR (~196 -> 2 waves/SIMD);
// the R11-proven register pipeline keeps latency off the critical path so few
// waves suffice. Zero main-loop barriers; merge epilogue at the end only.
__global__ __launch_bounds__(256, 2) void attn_kernel(const u16* __restrict__ qkv,
                                                      u16* __restrict__ o2) {
    __shared__ u16 Ps[4 * 64 * 68];      // 34816 B; reused as f32 reduction buffer
    __shared__ float Ls[4][64];          // per-wave row-sum partials
    int bh = blockIdx.y;
    int b = bh >> 3, h = bh & 7;
    int q0 = blockIdx.x * 64;
    int tid = threadIdx.x, lane = tid & 63, wid = tid >> 6;
    int quad = lane >> 4, n15 = lane & 15;
    const u16* Qp = qkv + (((size_t)b * 3 + 0) * 8 + h) * HSTRIDE;   // [l][c]
    const u16* Kf = qkv + (((size_t)b * 3 + 1) * 8 + h) * HSTRIDE;   // S^T-A frag order
    const u16* Vf = qkv + (((size_t)b * 3 + 2) * 8 + h) * HSTRIDE;   // PV-B frag order
    u16* Pw = Ps + wid * (64 * 68);      // wave-private P slice: 64 q x 64 keys

    bf16x8 vones;
#pragma unroll
    for (int z = 0; z < 8; ++z) vones[z] = (__bf16)1.0f;

    // Q fragments (B-operand for S^T) for all 64 q-rows, loaded once
    bf16x8 aq[4][2];
#pragma unroll
    for (int mf = 0; mf < 4; ++mf)
#pragma unroll
        for (int ks = 0; ks < 2; ++ks)
            aq[mf][ks] = *(const bf16x8*)
                &Qp[(size_t)(q0 + mf * 16 + n15) * 64 + ks * 32 + quad * 8];

    f32x4 oacc[4][4] = {};               // partial O over this wave's keys
    f32x4 osum[4] = {};                  // partial row sums (P x ones)

    // register-resident K/V fragments for the CURRENT iteration
    bf16x8 kf[4][2], vf[2][4];
    {
        int tile0 = wid * 32;
#pragma unroll
        for (int nf = 0; nf < 4; ++nf) {
            const u16* kb = Kf + (size_t)(tile0 + nf) * 1024;
            kf[nf][0] = *(const bf16x8*)&kb[lane * 8];
            kf[nf][1] = *(const bf16x8*)&kb[512 + lane * 8];
        }
#pragma unroll
        for (int sub = 0; sub < 2; ++sub) {
            const u16* vbb = Vf + (size_t)(wid * 16 + sub) * 2048;
#pragma unroll
            for (int nf2 = 0; nf2 < 4; ++nf2)
                vf[sub][nf2] = *(const bf16x8*)&vbb[nf2 * 512 + lane * 8];
        }
    }

    // wave's key strip: [wid*512, wid*512+512), processed in 64-key chunks
#pragma unroll
    for (int it = 0; it < 8; ++it) {
        // ---- S phase: uses kf (already in registers; no VMEM wait) ----
#pragma unroll
        for (int nf = 0; nf < 4; ++nf) {
#pragma unroll
            for (int mf = 0; mf < 4; ++mf) {
                f32x4 sT = {};
                sT = mfma16(kf[nf][0], aq[mf][0], sT);
                sT = mfma16(kf[nf][1], aq[mf][1], sT);
                float p0 = __builtin_amdgcn_exp2f(sT[0]);
                float p1 = __builtin_amdgcn_exp2f(sT[1]);
                float p2 = __builtin_amdgcn_exp2f(sT[2]);
                float p3 = __builtin_amdgcn_exp2f(sT[3]);
                uint2 pw;
                pw.x = pk2(p0, p1);
                pw.y = pk2(p2, p3);
                *(uint2*)&Pw[(mf * 16 + n15) * 68 + nf * 16 + quad * 4] = pw;
            }
        }
        // ---- prefetch K(it+1): kf is dead; cover = PV(it) + S-write(it+1) ----
        if (it < 7) {
            int tile0 = wid * 32 + (it + 1) * 4;
#pragma unroll
            for (int nf = 0; nf < 4; ++nf) {
                const u16* kb = Kf + (size_t)(tile0 + nf) * 1024;
                kf[nf][0] = *(const bf16x8*)&kb[lane * 8];
                kf[nf][1] = *(const bf16x8*)&kb[512 + lane * 8];
            }
        }
        // ---- PV phase: uses vf (in registers) + P from wave-private LDS ----
#pragma unroll
        for (int sub = 0; sub < 2; ++sub) {
            bf16x8 pa[4];
#pragma unroll
            for (int mf = 0; mf < 4; ++mf) {
                pa[mf] = *(const bf16x8*)&Pw[(mf * 16 + n15) * 68 + sub * 32 + quad * 8];
                osum[mf] = mfma16(pa[mf], vones, osum[mf]);
            }
#pragma unroll
            for (int nf2 = 0; nf2 < 4; ++nf2)
#pragma unroll
                for (int mf = 0; mf < 4; ++mf)
                    oacc[mf][nf2] = mfma16(pa[mf], vf[sub][nf2], oacc[mf][nf2]);
        }
        // ---- prefetch V(it+1): vf is dead; cover = S(it+1) ----
        if (it < 7) {
#pragma unroll
            for (int sub = 0; sub < 2; ++sub) {
                const u16* vbb = Vf + (size_t)(wid * 16 + (it + 1) * 2 + sub) * 2048;
#pragma unroll
                for (int nf2 = 0; nf2 < 4; ++nf2)
                    vf[sub][nf2] = *(const bf16x8*)&vbb[nf2 * 512 + lane * 8];
            }
        }
    }

    // ---- cross-wave merge ----
    // osum[mf][r] = rowsum for q-row mf*16+quad*4+r (identical across n15 lanes)
#pragma unroll
    for (int mf = 0; mf < 4; ++mf)
#pragma unroll
        for (int r = 0; r < 4; ++r)
            Ls[wid][mf * 16 + quad * 4 + r] = osum[mf][r];
    float* Ored = (float*)Ps;            // [4 waves][16 rows x stride 68 f32]
#pragma unroll
    for (int mf = 0; mf < 4; ++mf) {
        __syncthreads();                 // mf=0: all waves done with P + Ls written
        float* Od = Ored + wid * (16 * 68);
#pragma unroll
        for (int nf2 = 0; nf2 < 4; ++nf2)
#pragma unroll
            for (int r = 0; r < 4; ++r)
                Od[(quad * 4 + r) * 68 + nf2 * 16 + n15] = oacc[mf][nf2][r];
        __syncthreads();
        int row = tid >> 4, c0 = (tid & 15) * 4;
        float4 a0 = *(float4*)&Ored[0 * 1088 + row * 68 + c0];
        float4 a1 = *(float4*)&Ored[1 * 1088 + row * 68 + c0];
        float4 a2 = *(float4*)&Ored[2 * 1088 + row * 68 + c0];
        float4 a3 = *(float4*)&Ored[3 * 1088 + row * 68 + c0];
        float inv = 1.0f / (Ls[0][mf * 16 + row] + Ls[1][mf * 16 + row]
                          + Ls[2][mf * 16 + row] + Ls[3][mf * 16 + row]);
        ushort4 ov;
        ov.x = f2bf((a0.x + a1.x + a2.x + a3.x) * inv);
        ov.y = f2bf((a0.y + a1.y + a2.y + a3.y) * inv);
        ov.z = f2bf((a0.z + a1.z + a2.z + a3.z) * inv);
        ov.w = f2bf((a0.w + a1.w + a2.w + a3.w) * inv);
        *(ushort4*)&o2[((size_t)b * L_ + q0 + mf * 16 + row) * 512 + h * 64 + c0] = ov;
    }
}

// ---------- kernel 3: out GEMM  out[b,o,l] = sum_i w_out[o,i] o2[b,l,i] + b_out[o] ----------
// 64(o) x 128(l) tiles -> 512 blocks = 2 blocks/CU.
__global__ __launch_bounds__(256, 2) void out_gemm(const u16* __restrict__ wo,
                                                   const u16* __restrict__ o2,
                                                   const float* __restrict__ bout,
                                                   float* __restrict__ out) {
    __shared__ u16 As[4096], Bs[8192];
    int b  = blockIdx.z;
    int m0 = blockIdx.y * 64;    // o
    int n0 = blockIdx.x * 128;   // l
    int tid = threadIdx.x, lane = tid & 63, wid = tid >> 6;
    int quad = lane >> 4, n15 = lane & 15;
    const u16* Abase = wo + (size_t)m0 * 512;
    const u16* Bbase = o2 + ((size_t)b * L_ + n0) * 512;
    int mw = (wid & 1) * 32, nw = (wid >> 1) * 64;
    f32x4 acc[2][4] = {};
    for (int k0 = 0; k0 < 512; k0 += 64) {
        __syncthreads();
#pragma unroll
        for (int a = 0; a < 2; ++a) {
            int off = wid * 1024 + a * 512 + lane * 8;
            int row = off >> 6, col = off & 63;
            async16(Abase + (size_t)row * 512 + k0 + col, As + off);
        }
#pragma unroll
        for (int c = 0; c < 4; ++c) {
            int off = wid * 2048 + c * 512 + lane * 8;
            int row = off >> 6, col = off & 63;
            async16(Bbase + (size_t)row * 512 + k0 + col, Bs + off);
        }
        __syncthreads();
#pragma unroll
        for (int ks = 0; ks < 2; ++ks) {
            bf16x8 af[2], bfr[4];
#pragma unroll
            for (int i = 0; i < 2; ++i)
                af[i] = *(const bf16x8*)&As[(mw + i * 16 + n15) * 64 + ks * 32 + quad * 8];
#pragma unroll
            for (int j = 0; j < 4; ++j)
                bfr[j] = *(const bf16x8*)&Bs[(nw + j * 16 + n15) * 64 + ks * 32 + quad * 8];
#pragma unroll
            for (int i = 0; i < 2; ++i)
#pragma unroll
                for (int j = 0; j < 4; ++j)
                    acc[i][j] = mfma16(af[i], bfr[j], acc[i][j]);
        }
    }
#pragma unroll
    for (int i = 0; i < 2; ++i) {
#pragma unroll
        for (int r = 0; r < 4; ++r) {
            int o_ = m0 + mw + i * 16 + quad * 4 + r;
            float bias = bout[o_];
            float* dst = out + ((size_t)b * 512 + o_) * L_ + n0;
#pragma unroll
            for (int j = 0; j < 4; ++j) dst[nw + j * 16 + n15] = acc[i][j][r] + bias;
        }
    }
}

// ---------- workspace layout (u16 elements) ----------
#define OFF_XBT  ((size_t)0)                            // 4*2048*512   = 4194304
#define OFF_WQKV (OFF_XBT + (size_t)B_ * L_ * 512)      // 1536*512     =  786432
#define OFF_WOUT (OFF_WQKV + (size_t)1536 * 512)        // 512*512      =  262144
#define OFF_QKV  (OFF_WOUT + (size_t)512 * 512)         // 3*4*8*2048*64= 12582912
#define OFF_O2   (OFF_QKV + (size_t)3 * B_ * 8 * L_ * 64)  // 4*2048*512

extern "C" void kernel_launch(void* const* d_in, const int* in_sizes, int n_in,
                              void* d_out, int out_size, void* d_ws, size_t ws_size,
                              hipStream_t stream) {
    (void)in_sizes; (void)n_in; (void)out_size; (void)ws_size;
    const float* x    = (const float*)d_in[0];
    const float* wqkv = (const float*)d_in[1];
    const float* wout = (const float*)d_in[2];
    const float* bout = (const float*)d_in[3];
    float* out = (float*)d_out;
    u16* ws = (u16*)d_ws;
    u16* xbt   = ws + OFF_XBT;
    u16* wqkvb = ws + OFF_WQKV;
    u16* woutb = ws + OFF_WOUT;
    u16* qkv   = ws + OFF_QKV;
    u16* o2    = ws + OFF_O2;

    prep_kernel<<<2048, 256, 0, stream>>>(x, wqkv, wout, xbt, wqkvb, woutb);
    qkv_gemm<<<dim3(16, 12, 4), 256, 0, stream>>>(xbt, wqkvb, qkv);
    attn_kernel<<<dim3(32, 32), 256, 0, stream>>>(qkv, o2);
    out_gemm<<<dim3(16, 8, 4), 256, 0, stream>>>(woutb, o2, bout, out);
}